// Round 11
// baseline (667.768 us; speedup 1.0000x reference)
//
#include <hip/hip_runtime.h>

#define T_SZ 12
#define R_WG 16
#define NTHR 512
#define NWG  512   // 8192/16

typedef float  vf4 __attribute__((ext_vector_type(4)));
typedef float  vf2 __attribute__((ext_vector_type(2)));
typedef int    vi4 __attribute__((ext_vector_type(4)));
typedef __bf16 vbf8 __attribute__((ext_vector_type(8)));

__device__ __forceinline__ float sigm(float x){ return 1.f/(1.f+__expf(-x)); }
__device__ __forceinline__ float tanh_f(float x){
  float e=__expf(-2.f*fabsf(x)); float t=(1.f-e)/(1.f+e); return x<0.f?-t:t;
}
__device__ __forceinline__ unsigned short bf_hi(float f){
  unsigned int b=__float_as_uint(f);
  return (unsigned short)((b + 0x7fffu + ((b>>16)&1u))>>16);
}
__device__ __forceinline__ float bf_f(unsigned short h){
  return __uint_as_float(((unsigned int)h)<<16);
}
__device__ __forceinline__ vf4 mfma16(vi4 a, vi4 b, vf4 c){
  return __builtin_amdgcn_mfma_f32_16x16x32_bf16(
      __builtin_bit_cast(vbf8,a), __builtin_bit_cast(vbf8,b), c, 0, 0, 0);
}
__device__ __forceinline__ vi4 g16(const char* p){ return *(const vi4*)p; }

// split-bf16 h slots: slot*4096 + [split +2048] + (row*8 + ((k>>3)^(row&7)))*16 + (k&7)*2
__device__ __forceinline__ void a_read(const char* h9,int slot,int ks,int arow,int kb,vi4& Ah,vi4& Al){
  int blk=((ks<<2)+kb)^(arow&7);
  const char* p=h9+slot*4096+(arow*8+blk)*16;
  Ah=*(const vi4*)p; Al=*(const vi4*)(p+2048);
}
__device__ __forceinline__ void h9_w1(char* h9,int slot,int row,int k,float v){
  int off=slot*4096+(row*8+((k>>3)^(row&7)))*16+(k&7)*2;
  unsigned short hi=bf_hi(v);
  *(unsigned short*)(h9+off)=hi;
  *(unsigned short*)(h9+off+2048)=bf_hi(v-bf_f(hi));
}
__device__ __forceinline__ void h9_w2(char* h9,int slot,int row,int k0,float v0,float v1){
  int off=slot*4096+(row*8+((k0>>3)^(row&7)))*16+(k0&7)*2;
  unsigned short h0=bf_hi(v0),h1=bf_hi(v1);
  *(unsigned*)(h9+off)=(unsigned)h0|((unsigned)h1<<16);
  *(unsigned*)(h9+off+2048)=(unsigned)bf_hi(v0-bf_f(h0))|((unsigned)bf_hi(v1-bf_f(h1))<<16);
}
__device__ __forceinline__ float h9_rd(const char* h9,int slot,int row,int k){
  int off=slot*4096+(row*8+((k>>3)^(row&7)))*16+(k&7)*2;
  return bf_f(*(const unsigned short*)(h9+off))+bf_f(*(const unsigned short*)(h9+off+2048));
}

struct Ptrs {
  const float* ts; const float* gts;
  const unsigned short* Wm; const unsigned short* Wa;
  const float* Qb; const float* Fbp; const float* f1b;
  const float* m1w; const float* m1b; const float* m2w; const float* m2b;
  float* cg; float* out;
};

__global__ __launch_bounds__(NTHR,4) void fused_kernel(Ptrs P){
  __shared__ __align__(16) char  h9[45056];     // 11 slots x 4KB (0=h_tsa,1..8=nodes,9=h_ts,10=q/hbar)
  __shared__ __align__(16) float attn_s[1024];  // qk fp32 / p

  const int tid=threadIdx.x;
  const int r0=blockIdx.x*R_WG;
  const int w=tid>>6, ln=tid&63;
  const bool w4=(w<4);
  const int arow=ln&15, kb=ln>>4, qq=ln&3;
  const int rowN=(kb<<2)|qq;                               // nonlin row
  const int u0 = (w>>1)*16 + ((ln>>2)&3)*4 + (w&1)*2;      // nonlin u-pair base (even)
  const int colw = (w&3)*16 + arow;                        // attn C col (waves 0-3)
  const int crow0 = kb<<2;
  const char* Wmb=(const char*)P.Wm;
  const char* Wab=(const char*)P.Wa;
  // per-lane byte offsets of this wave's two LSTM N-block frags within a 16KB chunk
  const int b0=((2*w+0)*64+ln)*16, b1=((2*w+1)*64+ln)*16;
  // attention frag offsets (col-block = w&3): blocks cb*4 + {ks0hi,ks0lo,ks1hi,ks1lo}
  const int ab0=(((w&3)*4+0)*64+ln)*16, ab1=(((w&3)*4+1)*64+ln)*16;
  const int ab2=(((w&3)*4+2)*64+ln)*16, ab3=(((w&3)*4+3)*64+ln)*16;

  const float bQ =P.Qb [colw];
  const float bF =P.Fbp[colw];
  const float bf1v=P.f1b[colw];

  for(int i=tid;i<45056/16;i+=NTHR) ((vi4*)h9)[i]=(vi4){0,0,0,0};

  vf4 xa_c,xb_c,xa_n,xb_n;
  vf2 cv_c,cv_n;
  { // t0/l0 inputs
    const float* xs=P.ts+(size_t)(r0+arow)*192 + (kb&1)*8;
    xa_c=*(const vf4*)xs; xb_c=*(const vf4*)(xs+4);
  }
  cv_c=*(const vf2*)(P.cg + ((size_t)0*8192 + r0+rowN)*64 + u0);
  __syncthreads();   // h9 zeros visible

  // attention GEMM helper: K=64 from h9 slot, B frags direct from global chunk Wc
  auto attn_gemm=[&](const char* Wc,int slot,vf4 acc)->vf4{
    vi4 Ah,Al;
    vi4 B0=g16(Wc+ab0),B1=g16(Wc+ab1),B2=g16(Wc+ab2),B3=g16(Wc+ab3);
    a_read(h9,slot,0,arow,kb,Ah,Al);
    acc=mfma16(Ah,B0,acc); acc=mfma16(Al,B0,acc); acc=mfma16(Ah,B1,acc);
    a_read(h9,slot,1,arow,kb,Ah,Al);
    acc=mfma16(Ah,B2,acc); acc=mfma16(Al,B2,acc); acc=mfma16(Ah,B3,acc);
    return acc;
  };

  for(int t=0;t<T_SZ;t++){
    // ============ 9 LSTMs: B-frags straight from global (L2-hot), no staging ============
    #pragma unroll 1
    for(int l=0;l<9;l++){
      const int slotA=(l==0)?0:l;
      const char* Wl=Wmb + (((size_t)(l*12+t))*6)*16384;
      vf4 a0={0,0,0,0},a1={0,0,0,0};
      vi4 Ah,Al,Bh0,Bh1,Bl0,Bl1;
      // prefetch next x / c early (hidden under MFMAs)
      if(l<8){
        const float* xs=P.gts+(size_t)(r0+arow)*1536+(size_t)l*192+(size_t)t*16+(kb&1)*8;
        xa_n=*(const vf4*)xs; xb_n=*(const vf4*)(xs+4);
        cv_n=*(const vf2*)(P.cg+((size_t)(l+1)*8192+r0+rowN)*64+u0);
      }
      // ks0
      Bh0=g16(Wl+b0); Bh1=g16(Wl+b1); Bl0=g16(Wl+16384+b0); Bl1=g16(Wl+16384+b1);
      a_read(h9,slotA,0,arow,kb,Ah,Al);
      a0=mfma16(Ah,Bh0,a0); a0=mfma16(Al,Bh0,a0); a0=mfma16(Ah,Bl0,a0);
      a1=mfma16(Ah,Bh1,a1); a1=mfma16(Al,Bh1,a1); a1=mfma16(Ah,Bl1,a1);
      // ks1
      Bh0=g16(Wl+2*16384+b0); Bh1=g16(Wl+2*16384+b1);
      Bl0=g16(Wl+3*16384+b0); Bl1=g16(Wl+3*16384+b1);
      a_read(h9,slotA,1,arow,kb,Ah,Al);
      a0=mfma16(Ah,Bh0,a0); a0=mfma16(Al,Bh0,a0); a0=mfma16(Ah,Bl0,a0);
      a1=mfma16(Ah,Bh1,a1); a1=mfma16(Al,Bh1,a1); a1=mfma16(Ah,Bl1,a1);
      // ks2: A = [x(16) | bias-1 | 0]
      Bh0=g16(Wl+4*16384+b0); Bh1=g16(Wl+4*16384+b1);
      Bl0=g16(Wl+5*16384+b0); Bl1=g16(Wl+5*16384+b1);
      {
        vi4 xh,xl;
        if(kb<2){
          float xf[8]={xa_c[0],xa_c[1],xa_c[2],xa_c[3],xb_c[0],xb_c[1],xb_c[2],xb_c[3]};
          unsigned short hh[8],llo[8];
          #pragma unroll
          for(int j=0;j<8;j++){ hh[j]=bf_hi(xf[j]); llo[j]=bf_hi(xf[j]-bf_f(hh[j])); }
          xh=(vi4){(int)((unsigned)hh[0]|((unsigned)hh[1]<<16)),(int)((unsigned)hh[2]|((unsigned)hh[3]<<16)),
                   (int)((unsigned)hh[4]|((unsigned)hh[5]<<16)),(int)((unsigned)hh[6]|((unsigned)hh[7]<<16))};
          xl=(vi4){(int)((unsigned)llo[0]|((unsigned)llo[1]<<16)),(int)((unsigned)llo[2]|((unsigned)llo[3]<<16)),
                   (int)((unsigned)llo[4]|((unsigned)llo[5]<<16)),(int)((unsigned)llo[6]|((unsigned)llo[7]<<16))};
        } else if(kb==2){ xh=(vi4){0x3F80,0,0,0}; xl=(vi4){0,0,0,0}; }
        else            { xh=(vi4){0,0,0,0};     xl=(vi4){0,0,0,0}; }
        Ah=xh; Al=xl;
      }
      a0=mfma16(Ah,Bh0,a0); a0=mfma16(Al,Bh0,a0); a0=mfma16(Ah,Bl0,a0);
      a1=mfma16(Ah,Bh1,a1); a1=mfma16(Al,Bh1,a1); a1=mfma16(Ah,Bl1,a1);
      __syncthreads();   // all waves' A-reads of slot l complete before nonlin writes it
      // nonlin: quad-transpose; thread owns (rowN, u0) and (rowN, u0+1)
      {
        float hh2[2],cc2[2];
        float cold[2]={ (t==0)?0.f:cv_c[0], (t==0)?0.f:cv_c[1] };
        vf4 accs[2]={a0,a1};
        #pragma unroll
        for(int nt=0;nt<2;nt++){
          vf4 av=accs[nt];
          float v0=av[0],v1=av[1],v2=av[2],v3=av[3];
          auto sel=[&](int e)->float{ return e==0?v0:(e==1?v1:(e==2?v2:v3)); };
          float own=sel(qq);
          float r1=__shfl_xor(sel(qq^1),1);
          float r2=__shfl_xor(sel(qq^2),2);
          float r3=__shfl_xor(sel(qq^3),3);
          float gi=(qq==0)?own:((qq==1)?r1:((qq==2)?r2:r3));
          float gf=(qq==1)?own:((qq==0)?r1:((qq==3)?r2:r3));
          float gg=(qq==2)?own:((qq==3)?r1:((qq==0)?r2:r3));
          float go=(qq==3)?own:((qq==2)?r1:((qq==1)?r2:r3));
          float iv=sigm(gi),fv=sigm(gf),gv=tanh_f(gg),ov=sigm(go);
          float c2=fv*cold[nt]+iv*gv;
          cc2[nt]=c2; hh2[nt]=ov*tanh_f(c2);
        }
        *(vf2*)(P.cg + ((size_t)l*8192 + r0+rowN)*64 + u0) = (vf2){cc2[0],cc2[1]};
        h9_w2(h9,(l==0)?9:l,rowN,u0,hh2[0],hh2[1]);
      }
      xa_c=xa_n; xb_c=xb_n; cv_c=cv_n;
    }
    __syncthreads();   // slot8 (and all h) writes visible for attention

    // ============ attention / fusion (MFMA on waves 0-3) ============
    vf4 acA, facc;
    // phQ: q = h_ts@Qw.T + Qb -> slot10
    if(w4){
      acA=attn_gemm(Wab+0*16384, 9, (vf4){bQ,bQ,bQ,bQ});
      #pragma unroll
      for(int rg=0;rg<4;rg++) h9_w1(h9,10,crow0+rg,colw,acA[rg]);
    }
    __syncthreads();
    // phK: qk = q@(0.125*Kw) -> attn_s
    if(w4){
      acA=attn_gemm(Wab+1*16384, 10, (vf4){0,0,0,0});
      #pragma unroll
      for(int rg=0;rg<4;rg++) attn_s[(crow0+rg)*64+colw]=acA[rg];
    }
    __syncthreads();
    // phS: scores + softmax (two-phase p store)
    float pval=0.f;
    if(tid<128){
      int rr=tid>>3, nn=tid&7;
      const char* hp=h9+(nn+1)*4096;
      float s=0.f;
      #pragma unroll
      for(int kbl=0;kbl<8;kbl++){
        int blk=kbl^(rr&7);
        const char* pp=hp+(rr*8+blk)*16;
        vi4 hv=*(const vi4*)pp;
        vi4 lv=*(const vi4*)(pp+2048);
        const float* qkp=attn_s+rr*64+kbl*8;
        #pragma unroll
        for(int e=0;e<4;e++){
          unsigned hw=((const unsigned*)&hv)[e], lw=((const unsigned*)&lv)[e];
          float w0=__uint_as_float(hw<<16)+__uint_as_float(lw<<16);
          float w1=__uint_as_float(hw&0xffff0000u)+__uint_as_float(lw&0xffff0000u);
          s+=w0*qkp[e*2]+w1*qkp[e*2+1];
        }
      }
      float mx=s;
      mx=fmaxf(mx,__shfl_xor(mx,1));
      mx=fmaxf(mx,__shfl_xor(mx,2));
      mx=fmaxf(mx,__shfl_xor(mx,4));
      float e=__expf(s-mx);
      float sm=e;
      sm+=__shfl_xor(sm,1); sm+=__shfl_xor(sm,2); sm+=__shfl_xor(sm,4);
      pval=e/sm;
    }
    __syncthreads();
    if(tid<128) attn_s[tid]=pval;    // p[row][n]
    __syncthreads();
    // phH: hbar -> slot10 (8 waves x 2 rows)
    {
      int uu=tid&63, rbh=w*2;
      #pragma unroll
      for(int ri=0;ri<2;ri++){
        int row=rbh+ri;
        float sa=0.f;
        #pragma unroll
        for(int n=0;n<8;n++) sa+=attn_s[row*8+n]*h9_rd(h9,n+1,row,uu);
        h9_w1(h9,10,row,uu,sa);
      }
    }
    __syncthreads();
    // phC+phB: h_tsa = relu(VF*hbar + FB*h_ts + Fbp) -> slot0
    if(w4){
      acA=attn_gemm(Wab+2*16384, 10, (vf4){bF,bF,bF,bF});
      acA=attn_gemm(Wab+3*16384, 9, acA);
      #pragma unroll
      for(int rg=0;rg<4;rg++) h9_w1(h9,0,crow0+rg,colw,fmaxf(acA[rg],0.f));
    }
    if(t==T_SZ-1) break;
    // phF: f_ts = h_ts@F1B.T + f1b  (regs); phX: fusion reads
    vf4 g1,g2,g3,g4,g5,g6,g7,g8;
    if(w4){
      facc=attn_gemm(Wab+4*16384, 9, (vf4){bf1v,bf1v,bf1v,bf1v});
      const char* Wc=Wab+5*16384;
      vi4 B0=g16(Wc+ab0),B1=g16(Wc+ab1),B2=g16(Wc+ab2),B3=g16(Wc+ab3);
      vi4 Ah,Al;
      g1=facc;g2=facc;g3=facc;g4=facc;g5=facc;g6=facc;g7=facc;g8=facc;
      #define FUSE(gn,slot) \
        a_read(h9,slot,0,arow,kb,Ah,Al); \
        gn=mfma16(Ah,B0,gn); gn=mfma16(Al,B0,gn); gn=mfma16(Ah,B1,gn); \
        a_read(h9,slot,1,arow,kb,Ah,Al); \
        gn=mfma16(Ah,B2,gn); gn=mfma16(Al,B2,gn); gn=mfma16(Ah,B3,gn);
      FUSE(g1,1) FUSE(g2,2) FUSE(g3,3) FUSE(g4,4)
      FUSE(g5,5) FUSE(g6,6) FUSE(g7,7) FUSE(g8,8)
      #undef FUSE
    }
    __syncthreads();   // all fusion A-reads complete before slot overwrites
    if(w4){
      #pragma unroll
      for(int rg=0;rg<4;rg++){
        h9_w1(h9,1,crow0+rg,colw,fmaxf(g1[rg],0.f));
        h9_w1(h9,2,crow0+rg,colw,fmaxf(g2[rg],0.f));
        h9_w1(h9,3,crow0+rg,colw,fmaxf(g3[rg],0.f));
        h9_w1(h9,4,crow0+rg,colw,fmaxf(g4[rg],0.f));
        h9_w1(h9,5,crow0+rg,colw,fmaxf(g5[rg],0.f));
        h9_w1(h9,6,crow0+rg,colw,fmaxf(g6[rg],0.f));
        h9_w1(h9,7,crow0+rg,colw,fmaxf(g7[rg],0.f));
        h9_w1(h9,8,crow0+rg,colw,fmaxf(g8[rg],0.f));
      }
    }
    { // t+1 / l0 inputs
      const float* xs=P.ts+(size_t)(r0+arow)*192 + (size_t)(t+1)*16 + (kb&1)*8;
      xa_c=*(const vf4*)xs; xb_c=*(const vf4*)(xs+4);
      cv_c=*(const vf2*)(P.cg + ((size_t)0*8192 + r0+rowN)*64 + u0);
    }
    __syncthreads();   // fusion writes visible for next t
  }

  // ============ final MLP from slot0 (h_tsa) ============
  __syncthreads();
  {
    int rr=tid>>5, ii=tid&31;
    float h=P.m1b[ii];
    for(int k=0;k<64;k++) h+=h9_rd(h9,0,rr,k)*P.m1w[(size_t)ii*64+k];
    attn_s[rr*32+ii]=fmaxf(h,0.f);
  }
  __syncthreads();
  if(tid<R_WG){
    float s=P.m2b[0];
    for(int i=0;i<32;i++) s+=attn_s[tid*32+i]*P.m2w[i];
    P.out[r0+tid]=s;
  }
}

// ---- prep: LSTM weight chunks, split-bf16, frag layout; bias folded at k=80 ----
__global__ void prep_wm(const float* eW, const float* eU, const float* e2W, const float* e2U,
                        const float* emb_w, const float* eb_ih, const float* eb_hh,
                        const float* e2b_ih, const float* e2b_hh, const float* emb_b,
                        unsigned short* dst){
  int id=blockIdx.x*256+threadIdx.x;
  if(id>=108*3*16*64) return;
  int lane=id&63;
  int q=id>>6;
  int wnt=q&15;
  int q2=q>>4;
  int ks=q2%3;
  int lt=q2/3;
  int LL=lt/12, t=lt%12;
  int c15=lane&15;
  int u=(wnt>>2)*16+(c15>>2)*4+(wnt&3);
  int gt=c15&3;
  int jg=gt*64+u;
  const float* Whh=(LL==0)? eU+((size_t)t*256+jg)*64 : e2U+(((size_t)(LL-1)*12+t)*256+jg)*64;
  const float* Wih=(LL==0)? eW+((size_t)t*256+jg)*32 : e2W+(((size_t)(LL-1)*12+t)*256+jg)*32;
  float bsum;
  {
    float bi=(LL==0)? eb_ih[t*256+jg] : e2b_ih[((LL-1)*12+t)*256+jg];
    float bh=(LL==0)? eb_hh[t*256+jg] : e2b_hh[((LL-1)*12+t)*256+jg];
    float s=bi+bh;
    for(int i=0;i<32;i++) s+=Wih[i]*emb_b[i];
    bsum=s;
  }
  #pragma unroll
  for(int j=0;j<8;j++){
    int k=ks*32+(lane>>4)*8+j;
    float v;
    if(k<64) v=Whh[k];
    else if(k<80){
      int kx=k-64; float s=0.f;
      for(int i=0;i<32;i++) s+=Wih[i]*emb_w[i*16+kx];
      v=s;
    } else if(k==80) v=bsum;
    else v=0.f;
    unsigned short hi=bf_hi(v), lo=bf_hi(v-bf_f(hi));
    size_t base=((size_t)lt*6+ks*2)*8192 + ((size_t)wnt*64+lane)*8 + j;
    dst[base]=hi;
    dst[base+8192]=lo;
  }
}

// ---- prep: 6 attention/fusion chunks [colblk][ks][split][lane][8], + Fbp ----
__global__ void prep_attw(const float* Qw, const float* Kw, const float* Vw, const float* Vb,
                          const float* Fw, const float* Fb, const float* f1w,
                          unsigned short* dst, float* Fbp){
  int id=blockIdx.x*256+threadIdx.x;
  if(id<6144){
    int cidx=id>>10;
    int rem=id&1023;
    int block=rem>>6;
    int lane=rem&63;
    int ks=(block>>1)&1, s=block&1;
    int col=(block>>2)*16+(lane&15);
    #pragma unroll
    for(int j=0;j<8;j++){
      int k=ks*32+(lane>>4)*8+j;
      float v;
      if(cidx==0) v=Qw[col*64+k];
      else if(cidx==1) v=Kw[k*64+col]*0.125f;
      else if(cidx==2){ float sv=0.f; for(int m=0;m<64;m++) sv+=Fw[col*128+m]*Vw[m*64+k]; v=sv; }
      else if(cidx==3) v=Fw[col*128+64+k];
      else if(cidx==4) v=f1w[col*128+64+k];
      else             v=f1w[col*128+k];
      unsigned short hi=bf_hi(v);
      dst[(size_t)cidx*8192 + ((size_t)block*64+lane)*8 + j] = (s==0)? hi : bf_hi(v-bf_f(hi));
    }
  } else if(id<6144+64){
    int u=id-6144;
    float s=Fb[u];
    for(int m=0;m<64;m++) s+=Fw[u*128+m]*Vb[m];
    Fbp[u]=s;
  }
}

extern "C" void kernel_launch(void* const* d_in, const int* in_sizes, int n_in,
                              void* d_out, int out_size, void* d_ws, size_t ws_size,
                              hipStream_t stream){
  const float* ts      =(const float*)d_in[0];
  const float* gts     =(const float*)d_in[1];
  const float* emb_w   =(const float*)d_in[2];
  const float* emb_b   =(const float*)d_in[3];
  const float* attQ_w  =(const float*)d_in[4];
  const float* attQ_b  =(const float*)d_in[5];
  const float* attK_w  =(const float*)d_in[6];
  // d_in[7] attK_b: softmax-invariant, unused
  const float* attV_w  =(const float*)d_in[8];
  const float* attV_b  =(const float*)d_in[9];
  const float* attF_w  =(const float*)d_in[10];
  const float* attF_b  =(const float*)d_in[11];
  const float* fuse1_w =(const float*)d_in[12];
  const float* fuse1_b =(const float*)d_in[13];
  const float* enc_Wih =(const float*)d_in[14];
  const float* enc_Whh =(const float*)d_in[15];
  const float* enc_bih =(const float*)d_in[16];
  const float* enc_bhh =(const float*)d_in[17];
  const float* enc2_Wih=(const float*)d_in[18];
  const float* enc2_Whh=(const float*)d_in[19];
  const float* enc2_bih=(const float*)d_in[20];
  const float* enc2_bhh=(const float*)d_in[21];
  const float* mlp1_w  =(const float*)d_in[22];
  const float* mlp1_b  =(const float*)d_in[23];
  const float* mlp2_w  =(const float*)d_in[24];
  const float* mlp2_b  =(const float*)d_in[25];

  char* ws=(char*)d_ws;
  size_t off=0;
  unsigned short* Wm=(unsigned short*)(ws+off); off+=(size_t)108*6*8192*2;
  unsigned short* Wa=(unsigned short*)(ws+off); off+=(size_t)6*8192*2;
  float* Fbp=(float*)(ws+off); off+=64*4;
  float* cg =(float*)(ws+off); off+=(size_t)9*8192*64*4;

  prep_wm<<<(108*3*16*64+255)/256,256,0,stream>>>(enc_Wih,enc_Whh,enc2_Wih,enc2_Whh,emb_w,
                                                  enc_bih,enc_bhh,enc2_bih,enc2_bhh,emb_b,Wm);
  prep_attw<<<25,256,0,stream>>>(attQ_w,attK_w,attV_w,attV_b,attF_w,attF_b,fuse1_w,Wa,Fbp);

  Ptrs P;
  P.ts=ts; P.gts=gts; P.Wm=Wm; P.Wa=Wa;
  P.Qb=attQ_b; P.Fbp=Fbp; P.f1b=fuse1_b;
  P.m1w=mlp1_w; P.m1b=mlp1_b; P.m2w=mlp2_w; P.m2b=mlp2_b;
  P.cg=cg; P.out=(float*)d_out;

  fused_kernel<<<NWG,NTHR,0,stream>>>(P);
}

// Round 12
// 595.158 us; speedup vs baseline: 1.1220x; 1.1220x over previous
//
#include <hip/hip_runtime.h>

#define T_SZ 12
#define R_WG 16
#define NTHR 512
#define NWG  512   // 8192/16

typedef float  vf4 __attribute__((ext_vector_type(4)));
typedef int    vi4 __attribute__((ext_vector_type(4)));
typedef __bf16 vbf8 __attribute__((ext_vector_type(8)));

__device__ __forceinline__ float sigm(float x){ return 1.f/(1.f+__expf(-x)); }
__device__ __forceinline__ float tanh_f(float x){
  float e=__expf(-2.f*fabsf(x)); float t=(1.f-e)/(1.f+e); return x<0.f?-t:t;
}
__device__ __forceinline__ unsigned short bf_hi(float f){
  unsigned int b=__float_as_uint(f);
  return (unsigned short)((b + 0x7fffu + ((b>>16)&1u))>>16);
}
__device__ __forceinline__ float bf_f(unsigned short h){
  return __uint_as_float(((unsigned int)h)<<16);
}
__device__ __forceinline__ vf4 mfma16(vi4 a, vi4 b, vf4 c){
  return __builtin_amdgcn_mfma_f32_16x16x32_bf16(
      __builtin_bit_cast(vbf8,a), __builtin_bit_cast(vbf8,b), c, 0, 0, 0);
}
__device__ __forceinline__ vi4 g16(const char* p){ return *(const vi4*)p; }

// split-bf16 h slots: slot*4096 + [split +2048] + (row*8 + ((k>>3)^(row&7)))*16 + (k&7)*2
__device__ __forceinline__ void a_read(const char* h9,int slot,int ks,int arow,int kb,vi4& Ah,vi4& Al){
  int blk=((ks<<2)+kb)^(arow&7);
  const char* p=h9+slot*4096+(arow*8+blk)*16;
  Ah=*(const vi4*)p; Al=*(const vi4*)(p+2048);
}
__device__ __forceinline__ void h9_w1(char* h9,int slot,int row,int k,float v){
  int off=slot*4096+(row*8+((k>>3)^(row&7)))*16+(k&7)*2;
  unsigned short hi=bf_hi(v);
  *(unsigned short*)(h9+off)=hi;
  *(unsigned short*)(h9+off+2048)=bf_hi(v-bf_f(hi));
}
__device__ __forceinline__ void h9_w2(char* h9,int slot,int row,int k0,float v0,float v1){
  int off=slot*4096+(row*8+((k0>>3)^(row&7)))*16+(k0&7)*2;
  unsigned short h0=bf_hi(v0),h1=bf_hi(v1);
  *(unsigned*)(h9+off)=(unsigned)h0|((unsigned)h1<<16);
  *(unsigned*)(h9+off+2048)=(unsigned)bf_hi(v0-bf_f(h0))|((unsigned)bf_hi(v1-bf_f(h1))<<16);
}
__device__ __forceinline__ float h9_rd(const char* h9,int slot,int row,int k){
  int off=slot*4096+(row*8+((k>>3)^(row&7)))*16+(k&7)*2;
  return bf_f(*(const unsigned short*)(h9+off))+bf_f(*(const unsigned short*)(h9+off+2048));
}

struct Ptrs {
  const unsigned short* Wm; const unsigned short* Wa; const unsigned short* Xf;
  const float* Qb; const float* Fbp; const float* f1b;
  const float* m1w; const float* m1b; const float* m2w; const float* m2b;
  float* out;
};

__global__ __launch_bounds__(NTHR,4) void fused_kernel(Ptrs P){
  __shared__ __align__(16) char  h9[45056];     // 11 slots x 4KB (0=h_tsa,1..8=nodes,9=h_ts,10=q/hbar)
  __shared__ __align__(16) float attn_s[1024];  // qk fp32 / p

  const int tid=threadIdx.x;
  const int r0=blockIdx.x*R_WG;
  const int w=tid>>6, ln=tid&63;
  const bool w4=(w<4);
  const int arow=ln&15, kb=ln>>4, qq=ln&3;
  const int rowN=(kb<<2)|qq;                               // nonlin row
  const int u0 = (w>>1)*16 + ((ln>>2)&3)*4 + (w&1)*2;      // nonlin u-pair base (even)
  const int colw = (w&3)*16 + arow;                        // attn C col
  const int crow0 = kb<<2;
  const char* Wmb=(const char*)P.Wm;
  const char* Wab=(const char*)P.Wa;
  const char* Xfb=(const char*)P.Xf + (size_t)(r0+arow)*9*24*32;
  const int b0=((2*w+0)*64+ln)*16, b1=((2*w+1)*64+ln)*16;
  const int ab0=(((w&3)*4+0)*64+ln)*16, ab1=(((w&3)*4+1)*64+ln)*16;
  const int ab2=(((w&3)*4+2)*64+ln)*16, ab3=(((w&3)*4+3)*64+ln)*16;

  const float bQ =P.Qb [colw];
  const float bF =P.Fbp[colw];
  const float bf1v=P.f1b[colw];

  float cst[9][2];   // c-state fully in registers (static indices via full unroll)
  #pragma unroll
  for(int l=0;l<9;l++){ cst[l][0]=0.f; cst[l][1]=0.f; }

  for(int i=tid;i<45056/16;i+=NTHR) ((vi4*)h9)[i]=(vi4){0,0,0,0};
  __syncthreads();   // h9 zeros visible

  auto attn_gemm=[&](const char* Wc,int slot,vf4 acc)->vf4{
    vi4 Ah,Al;
    vi4 B0=g16(Wc+ab0),B1=g16(Wc+ab1),B2=g16(Wc+ab2),B3=g16(Wc+ab3);
    a_read(h9,slot,0,arow,kb,Ah,Al);
    acc=mfma16(Ah,B0,acc); acc=mfma16(Al,B0,acc); acc=mfma16(Ah,B1,acc);
    a_read(h9,slot,1,arow,kb,Ah,Al);
    acc=mfma16(Ah,B2,acc); acc=mfma16(Al,B2,acc); acc=mfma16(Ah,B3,acc);
    return acc;
  };

  for(int t=0;t<T_SZ;t++){
    // ============ 9 LSTMs, fully unrolled; x A-frags precomputed; c in regs ============
    #pragma unroll
    for(int l=0;l<9;l++){
      const int slotA=(l==0)?0:l;
      const char* Wl=Wmb + ((size_t)(l*12+t)*6)*16384;
      vf4 a0={0,0,0,0},a1={0,0,0,0};
      vi4 Ah,Al,Bh0,Bh1,Bl0,Bl1;
      // ks0
      Bh0=g16(Wl+b0); Bh1=g16(Wl+b1); Bl0=g16(Wl+16384+b0); Bl1=g16(Wl+16384+b1);
      a_read(h9,slotA,0,arow,kb,Ah,Al);
      a0=mfma16(Ah,Bh0,a0); a0=mfma16(Al,Bh0,a0); a0=mfma16(Ah,Bl0,a0);
      a1=mfma16(Ah,Bh1,a1); a1=mfma16(Al,Bh1,a1); a1=mfma16(Ah,Bl1,a1);
      // ks1
      Bh0=g16(Wl+2*16384+b0); Bh1=g16(Wl+2*16384+b1);
      Bl0=g16(Wl+3*16384+b0); Bl1=g16(Wl+3*16384+b1);
      a_read(h9,slotA,1,arow,kb,Ah,Al);
      a0=mfma16(Ah,Bh0,a0); a0=mfma16(Al,Bh0,a0); a0=mfma16(Ah,Bl0,a0);
      a1=mfma16(Ah,Bh1,a1); a1=mfma16(Al,Bh1,a1); a1=mfma16(Ah,Bl1,a1);
      // ks2: A = [x(16) | bias-1 | 0], x frags pre-split in ws
      Bh0=g16(Wl+4*16384+b0); Bh1=g16(Wl+4*16384+b1);
      Bl0=g16(Wl+5*16384+b0); Bl1=g16(Wl+5*16384+b1);
      if(kb<2){
        const char* xp=Xfb + (size_t)(l*24 + t*2 + kb)*32;
        Ah=g16(xp); Al=g16(xp+16);
      } else if(kb==2){ Ah=(vi4){0x3F80,0,0,0}; Al=(vi4){0,0,0,0}; }
      else            { Ah=(vi4){0,0,0,0};     Al=(vi4){0,0,0,0}; }
      a0=mfma16(Ah,Bh0,a0); a0=mfma16(Al,Bh0,a0); a0=mfma16(Ah,Bl0,a0);
      a1=mfma16(Ah,Bh1,a1); a1=mfma16(Al,Bh1,a1); a1=mfma16(Ah,Bl1,a1);
      if(l>0) __syncthreads();   // all waves' A-reads of slot l done before its overwrite
                                 // (l==0 writes slot 9: disjoint, no barrier needed)
      // nonlin: quad-transpose; thread owns (rowN, u0) and (rowN, u0+1)
      {
        float hh2[2],cc2[2];
        vf4 accs[2]={a0,a1};
        #pragma unroll
        for(int nt=0;nt<2;nt++){
          vf4 av=accs[nt];
          float v0=av[0],v1=av[1],v2=av[2],v3=av[3];
          auto sel=[&](int e)->float{ return e==0?v0:(e==1?v1:(e==2?v2:v3)); };
          float own=sel(qq);
          float r1=__shfl_xor(sel(qq^1),1);
          float r2=__shfl_xor(sel(qq^2),2);
          float r3=__shfl_xor(sel(qq^3),3);
          float gi=(qq==0)?own:((qq==1)?r1:((qq==2)?r2:r3));
          float gf=(qq==1)?own:((qq==0)?r1:((qq==3)?r2:r3));
          float gg=(qq==2)?own:((qq==3)?r1:((qq==0)?r2:r3));
          float go=(qq==3)?own:((qq==2)?r1:((qq==1)?r2:r3));
          float iv=sigm(gi),fv=sigm(gf),gv=tanh_f(gg),ov=sigm(go);
          float c2=fv*cst[l][nt]+iv*gv;
          cc2[nt]=c2; hh2[nt]=ov*tanh_f(c2);
        }
        cst[l][0]=cc2[0]; cst[l][1]=cc2[1];
        h9_w2(h9,(l==0)?9:l,rowN,u0,hh2[0],hh2[1]);
      }
    }
    __syncthreads();   // all h writes visible for attention/fusion

    // ===== attention (waves 0-3) runs CONCURRENTLY with f_ts+fusion (waves 4-7) =====
    vf4 acA;
    vf4 facc,g1,g2,g3,g4,g5,g6,g7,g8;
    const bool dofuse=(t<T_SZ-1);
    if(w4){
      // phQ: q = h_ts@Qw.T + Qb -> slot10
      acA=attn_gemm(Wab+0*16384, 9, (vf4){bQ,bQ,bQ,bQ});
      #pragma unroll
      for(int rg=0;rg<4;rg++) h9_w1(h9,10,crow0+rg,colw,acA[rg]);
    } else if(dofuse){
      // phF: f_ts = h_ts@F1B.T + f1b ; phX-compute: fusion g_n into regs
      facc=attn_gemm(Wab+4*16384, 9, (vf4){bf1v,bf1v,bf1v,bf1v});
      const char* Wc=Wab+5*16384;
      vi4 B0=g16(Wc+ab0),B1=g16(Wc+ab1),B2=g16(Wc+ab2),B3=g16(Wc+ab3);
      vi4 Ah,Al;
      g1=facc;g2=facc;g3=facc;g4=facc;g5=facc;g6=facc;g7=facc;g8=facc;
      #define FUSE(gn,slot) \
        a_read(h9,slot,0,arow,kb,Ah,Al); \
        gn=mfma16(Ah,B0,gn); gn=mfma16(Al,B0,gn); gn=mfma16(Ah,B1,gn); \
        a_read(h9,slot,1,arow,kb,Ah,Al); \
        gn=mfma16(Ah,B2,gn); gn=mfma16(Al,B2,gn); gn=mfma16(Ah,B3,gn);
      FUSE(g1,1) FUSE(g2,2) FUSE(g3,3) FUSE(g4,4)
      FUSE(g5,5) FUSE(g6,6) FUSE(g7,7) FUSE(g8,8)
      #undef FUSE
    }
    __syncthreads();
    // phK: qk = q@(0.125*Kw) -> attn_s
    if(w4){
      acA=attn_gemm(Wab+1*16384, 10, (vf4){0,0,0,0});
      #pragma unroll
      for(int rg=0;rg<4;rg++) attn_s[(crow0+rg)*64+colw]=acA[rg];
    }
    __syncthreads();
    // phS: scores + softmax (two-phase p store)
    float pval=0.f;
    if(tid<128){
      int rr=tid>>3, nn=tid&7;
      const char* hp=h9+(nn+1)*4096;
      float s=0.f;
      #pragma unroll
      for(int kbl=0;kbl<8;kbl++){
        int blk=kbl^(rr&7);
        const char* pp=hp+(rr*8+blk)*16;
        vi4 hv=*(const vi4*)pp;
        vi4 lv=*(const vi4*)(pp+2048);
        const float* qkp=attn_s+rr*64+kbl*8;
        #pragma unroll
        for(int e=0;e<4;e++){
          unsigned hw=((const unsigned*)&hv)[e], lw=((const unsigned*)&lv)[e];
          float w0=__uint_as_float(hw<<16)+__uint_as_float(lw<<16);
          float w1=__uint_as_float(hw&0xffff0000u)+__uint_as_float(lw&0xffff0000u);
          s+=w0*qkp[e*2]+w1*qkp[e*2+1];
        }
      }
      float mx=s;
      mx=fmaxf(mx,__shfl_xor(mx,1));
      mx=fmaxf(mx,__shfl_xor(mx,2));
      mx=fmaxf(mx,__shfl_xor(mx,4));
      float e=__expf(s-mx);
      float sm=e;
      sm+=__shfl_xor(sm,1); sm+=__shfl_xor(sm,2); sm+=__shfl_xor(sm,4);
      pval=e/sm;
    }
    __syncthreads();
    if(tid<128) attn_s[tid]=pval;    // p[row][n]
    __syncthreads();
    // phH: hbar -> slot10 (waves 0-3, 4 rows each)
    if(w4){
      #pragma unroll
      for(int ri=0;ri<4;ri++){
        int row=w*4+ri;
        float sa=0.f;
        #pragma unroll
        for(int n=0;n<8;n++) sa+=attn_s[row*8+n]*h9_rd(h9,n+1,row,ln);
        h9_w1(h9,10,row,ln,sa);
      }
    }
    __syncthreads();
    // phC+phB (w0-3) -> slot0 ; CONCURRENT fused-h writes (w4-7) -> slots 1..8
    if(w4){
      acA=attn_gemm(Wab+2*16384, 10, (vf4){bF,bF,bF,bF});
      acA=attn_gemm(Wab+3*16384, 9, acA);
      #pragma unroll
      for(int rg=0;rg<4;rg++) h9_w1(h9,0,crow0+rg,colw,fmaxf(acA[rg],0.f));
    } else if(dofuse){
      #pragma unroll
      for(int rg=0;rg<4;rg++){
        h9_w1(h9,1,crow0+rg,colw,fmaxf(g1[rg],0.f));
        h9_w1(h9,2,crow0+rg,colw,fmaxf(g2[rg],0.f));
        h9_w1(h9,3,crow0+rg,colw,fmaxf(g3[rg],0.f));
        h9_w1(h9,4,crow0+rg,colw,fmaxf(g4[rg],0.f));
        h9_w1(h9,5,crow0+rg,colw,fmaxf(g5[rg],0.f));
        h9_w1(h9,6,crow0+rg,colw,fmaxf(g6[rg],0.f));
        h9_w1(h9,7,crow0+rg,colw,fmaxf(g7[rg],0.f));
        h9_w1(h9,8,crow0+rg,colw,fmaxf(g8[rg],0.f));
      }
    }
    __syncthreads();   // all state writes visible for next t / final MLP
  }

  // ============ final MLP from slot0 (h_tsa) ============
  {
    int rr=tid>>5, ii=tid&31;
    float h=P.m1b[ii];
    for(int k=0;k<64;k++) h+=h9_rd(h9,0,rr,k)*P.m1w[(size_t)ii*64+k];
    attn_s[rr*32+ii]=fmaxf(h,0.f);
  }
  __syncthreads();
  if(tid<R_WG){
    float s=P.m2b[0];
    for(int i=0;i<32;i++) s+=attn_s[tid*32+i]*P.m2w[i];
    P.out[r0+tid]=s;
  }
}

// ---- prep: LSTM weight chunks, split-bf16, frag layout; bias folded at k=80 ----
__global__ void prep_wm(const float* eW, const float* eU, const float* e2W, const float* e2U,
                        const float* emb_w, const float* eb_ih, const float* eb_hh,
                        const float* e2b_ih, const float* e2b_hh, const float* emb_b,
                        unsigned short* dst){
  int id=blockIdx.x*256+threadIdx.x;
  if(id>=108*3*16*64) return;
  int lane=id&63;
  int q=id>>6;
  int wnt=q&15;
  int q2=q>>4;
  int ks=q2%3;
  int lt=q2/3;
  int LL=lt/12, t=lt%12;
  int c15=lane&15;
  int u=(wnt>>2)*16+(c15>>2)*4+(wnt&3);
  int gt=c15&3;
  int jg=gt*64+u;
  const float* Whh=(LL==0)? eU+((size_t)t*256+jg)*64 : e2U+(((size_t)(LL-1)*12+t)*256+jg)*64;
  const float* Wih=(LL==0)? eW+((size_t)t*256+jg)*32 : e2W+(((size_t)(LL-1)*12+t)*256+jg)*32;
  float bsum;
  {
    float bi=(LL==0)? eb_ih[t*256+jg] : e2b_ih[((LL-1)*12+t)*256+jg];
    float bh=(LL==0)? eb_hh[t*256+jg] : e2b_hh[((LL-1)*12+t)*256+jg];
    float s=bi+bh;
    for(int i=0;i<32;i++) s+=Wih[i]*emb_b[i];
    bsum=s;
  }
  #pragma unroll
  for(int j=0;j<8;j++){
    int k=ks*32+(lane>>4)*8+j;
    float v;
    if(k<64) v=Whh[k];
    else if(k<80){
      int kx=k-64; float s=0.f;
      for(int i=0;i<32;i++) s+=Wih[i]*emb_w[i*16+kx];
      v=s;
    } else if(k==80) v=bsum;
    else v=0.f;
    unsigned short hi=bf_hi(v), lo=bf_hi(v-bf_f(hi));
    size_t base=((size_t)lt*6+ks*2)*8192 + ((size_t)wnt*64+lane)*8 + j;
    dst[base]=hi;
    dst[base+8192]=lo;
  }
}

// ---- prep: 6 attention/fusion chunks [colblk][ks][split][lane][8], + Fbp ----
__global__ void prep_attw(const float* Qw, const float* Kw, const float* Vw, const float* Vb,
                          const float* Fw, const float* Fb, const float* f1w,
                          unsigned short* dst, float* Fbp){
  int id=blockIdx.x*256+threadIdx.x;
  if(id<6144){
    int cidx=id>>10;
    int rem=id&1023;
    int block=rem>>6;
    int lane=rem&63;
    int ks=(block>>1)&1, s=block&1;
    int col=(block>>2)*16+(lane&15);
    #pragma unroll
    for(int j=0;j<8;j++){
      int k=ks*32+(lane>>4)*8+j;
      float v;
      if(cidx==0) v=Qw[col*64+k];
      else if(cidx==1) v=Kw[k*64+col]*0.125f;
      else if(cidx==2){ float sv=0.f; for(int m=0;m<64;m++) sv+=Fw[col*128+m]*Vw[m*64+k]; v=sv; }
      else if(cidx==3) v=Fw[col*128+64+k];
      else if(cidx==4) v=f1w[col*128+64+k];
      else             v=f1w[col*128+k];
      unsigned short hi=bf_hi(v);
      dst[(size_t)cidx*8192 + ((size_t)block*64+lane)*8 + j] = (s==0)? hi : bf_hi(v-bf_f(hi));
    }
  } else if(id<6144+64){
    int u=id-6144;
    float s=Fb[u];
    for(int m=0;m<64;m++) s+=Fw[u*128+m]*Vb[m];
    Fbp[u]=s;
  }
}

// ---- prep: x A-fragments pre-split to bf16 hi/lo: [b][src 0..8][t][kb]{hi 16B, lo 16B} ----
__global__ void prep_xf(const float* ts, const float* gts, unsigned short* xf){
  int id=blockIdx.x*256+threadIdx.x;
  if(id>=8192*9*24) return;
  int kb=id&1;
  int t=(id>>1)%12;
  int q=id/24;
  int src=q%9;
  int b=q/9;
  const float* s=(src==0)? ts+(size_t)b*192+(size_t)t*16+kb*8
                         : gts+(size_t)b*1536+(size_t)(src-1)*192+(size_t)t*16+kb*8;
  unsigned short* d=xf+(size_t)id*16;
  #pragma unroll
  for(int j=0;j<8;j++){
    float f=s[j];
    unsigned short hi=bf_hi(f);
    d[j]=hi;
    d[8+j]=bf_hi(f-bf_f(hi));
  }
}

extern "C" void kernel_launch(void* const* d_in, const int* in_sizes, int n_in,
                              void* d_out, int out_size, void* d_ws, size_t ws_size,
                              hipStream_t stream){
  const float* ts      =(const float*)d_in[0];
  const float* gts     =(const float*)d_in[1];
  const float* emb_w   =(const float*)d_in[2];
  const float* emb_b   =(const float*)d_in[3];
  const float* attQ_w  =(const float*)d_in[4];
  const float* attQ_b  =(const float*)d_in[5];
  const float* attK_w  =(const float*)d_in[6];
  // d_in[7] attK_b: softmax-invariant, unused
  const float* attV_w  =(const float*)d_in[8];
  const float* attV_b  =(const float*)d_in[9];
  const float* attF_w  =(const float*)d_in[10];
  const float* attF_b  =(const float*)d_in[11];
  const float* fuse1_w =(const float*)d_in[12];
  const float* fuse1_b =(const float*)d_in[13];
  const float* enc_Wih =(const float*)d_in[14];
  const float* enc_Whh =(const float*)d_in[15];
  const float* enc_bih =(const float*)d_in[16];
  const float* enc_bhh =(const float*)d_in[17];
  const float* enc2_Wih=(const float*)d_in[18];
  const float* enc2_Whh=(const float*)d_in[19];
  const float* enc2_bih=(const float*)d_in[20];
  const float* enc2_bhh=(const float*)d_in[21];
  const float* mlp1_w  =(const float*)d_in[22];
  const float* mlp1_b  =(const float*)d_in[23];
  const float* mlp2_w  =(const float*)d_in[24];
  const float* mlp2_b  =(const float*)d_in[25];

  char* ws=(char*)d_ws;
  size_t off=0;
  unsigned short* Wm=(unsigned short*)(ws+off); off+=(size_t)108*6*8192*2;
  unsigned short* Wa=(unsigned short*)(ws+off); off+=(size_t)6*8192*2;
  float* Fbp=(float*)(ws+off); off+=64*4;
  unsigned short* Xf=(unsigned short*)(ws+off); off+=(size_t)8192*9*24*16*2;

  prep_wm<<<(108*3*16*64+255)/256,256,0,stream>>>(enc_Wih,enc_Whh,enc2_Wih,enc2_Whh,emb_w,
                                                  enc_bih,enc_bhh,enc2_bih,enc2_bhh,emb_b,Wm);
  prep_attw<<<25,256,0,stream>>>(attQ_w,attK_w,attV_w,attV_b,attF_w,attF_b,fuse1_w,Wa,Fbp);
  prep_xf<<<(8192*9*24+255)/256,256,0,stream>>>(ts,gts,Xf);

  Ptrs P;
  P.Wm=Wm; P.Wa=Wa; P.Xf=Xf;
  P.Qb=attQ_b; P.Fbp=Fbp; P.f1b=fuse1_b;
  P.m1w=mlp1_w; P.m1b=mlp1_b; P.m2w=mlp2_w; P.m2b=mlp2_b;
  P.out=(float*)d_out;

  fused_kernel<<<NWG,NTHR,0,stream>>>(P);
}

// Round 14
// 586.228 us; speedup vs baseline: 1.1391x; 1.0152x over previous
//
#include <hip/hip_runtime.h>

#define T_SZ 12
#define R_WG 16
#define NTHR 512
#define NWG  512   // 8192/16

typedef float  vf4 __attribute__((ext_vector_type(4)));
typedef int    vi4 __attribute__((ext_vector_type(4)));
typedef __bf16 vbf8 __attribute__((ext_vector_type(8)));

__device__ __forceinline__ float sigm(float x){ return 1.f/(1.f+__expf(-x)); }
__device__ __forceinline__ float tanh_f(float x){
  float e=__expf(-2.f*fabsf(x)); float t=(1.f-e)/(1.f+e); return x<0.f?-t:t;
}
__device__ __forceinline__ unsigned short bf_hi(float f){
  unsigned int b=__float_as_uint(f);
  return (unsigned short)((b + 0x7fffu + ((b>>16)&1u))>>16);
}
__device__ __forceinline__ float bf_f(unsigned short h){
  return __uint_as_float(((unsigned int)h)<<16);
}
__device__ __forceinline__ vf4 mfma16(vi4 a, vi4 b, vf4 c){
  return __builtin_amdgcn_mfma_f32_16x16x32_bf16(
      __builtin_bit_cast(vbf8,a), __builtin_bit_cast(vbf8,b), c, 0, 0, 0);
}
__device__ __forceinline__ vi4 g16(const char* p){ return *(const vi4*)p; }

// split-bf16 h slots: slot*4096 + [split +2048] + (row*8 + ((k>>3)^(row&7)))*16 + (k&7)*2
// slots: 0=h_tsa, 1..8=X fused nodes, 9=h_ts, 10=R (qk fp32 / hbar), 11..18=Y raw nodes
__device__ __forceinline__ void a_read(const char* h9,int slot,int ks,int arow,int kb,vi4& Ah,vi4& Al){
  int blk=((ks<<2)+kb)^(arow&7);
  const char* p=h9+slot*4096+(arow*8+blk)*16;
  Ah=*(const vi4*)p; Al=*(const vi4*)(p+2048);
}
__device__ __forceinline__ void h9_w1(char* h9,int slot,int row,int k,float v){
  int off=slot*4096+(row*8+((k>>3)^(row&7)))*16+(k&7)*2;
  unsigned short hi=bf_hi(v);
  *(unsigned short*)(h9+off)=hi;
  *(unsigned short*)(h9+off+2048)=bf_hi(v-bf_f(hi));
}
__device__ __forceinline__ void h9_w2(char* h9,int slot,int row,int k0,float v0,float v1){
  int off=slot*4096+(row*8+((k0>>3)^(row&7)))*16+(k0&7)*2;
  unsigned short h0=bf_hi(v0),h1=bf_hi(v1);
  *(unsigned*)(h9+off)=(unsigned)h0|((unsigned)h1<<16);
  *(unsigned*)(h9+off+2048)=(unsigned)bf_hi(v0-bf_f(h0))|((unsigned)bf_hi(v1-bf_f(h1))<<16);
}
__device__ __forceinline__ float h9_rd(const char* h9,int slot,int row,int k){
  int off=slot*4096+(row*8+((k>>3)^(row&7)))*16+(k&7)*2;
  return bf_f(*(const unsigned short*)(h9+off))+bf_f(*(const unsigned short*)(h9+off+2048));
}

struct Ptrs {
  const unsigned short* Wm; const unsigned short* Wa; const unsigned short* Xf;
  const float* Fbp; const float* bqk; const float* f1b;
  const float* m1w; const float* m1b; const float* m2w; const float* m2b;
  float* out;
};

__global__ __launch_bounds__(NTHR,4) void fused_kernel(Ptrs P){
  __shared__ __align__(16) char  h9[77824];     // 19 slots x 4KB
  __shared__ __align__(16) float pbuf[128];

  const int tid=threadIdx.x;
  const int r0=blockIdx.x*R_WG;
  const int w=tid>>6, ln=tid&63;
  const bool w4=(w<4);
  const int arow=ln&15, kb=ln>>4, qq=ln&3;
  const int rowN=(kb<<2)|qq;                               // nonlin row
  const int u0 = (w>>1)*16 + ((ln>>2)&3)*4 + (w&1)*2;      // nonlin u-pair base (even)
  const int colw = (w&3)*16 + arow;                        // attn C col
  const int crow0 = kb<<2;
  const char* Wmb=(const char*)P.Wm;
  const char* Wab=(const char*)P.Wa;
  const char* Xfb=(const char*)P.Xf + (size_t)(r0+arow)*9*24*32;
  float* qkf=(float*)(h9+10*4096);                         // region R as fp32 qk
  const int b0=((2*w+0)*64+ln)*16, b1=((2*w+1)*64+ln)*16;
  const int ab0=(((w&3)*4+0)*64+ln)*16, ab1=(((w&3)*4+1)*64+ln)*16;
  const int ab2=(((w&3)*4+2)*64+ln)*16, ab3=(((w&3)*4+3)*64+ln)*16;

  const float bQK=P.bqk[colw];
  const float bF =P.Fbp[colw];
  const float bf1v=P.f1b[colw];

  float cst[9][2];
  #pragma unroll
  for(int l=0;l<9;l++){ cst[l][0]=0.f; cst[l][1]=0.f; }

  for(int i=tid;i<77824/16;i+=NTHR) ((vi4*)h9)[i]=(vi4){0,0,0,0};
  __syncthreads();   // zeros visible

  auto attn_gemm=[&](const char* Wc,int slot,vf4 acc)->vf4{
    vi4 Ah,Al;
    vi4 B0=g16(Wc+ab0),B1=g16(Wc+ab1),B2=g16(Wc+ab2),B3=g16(Wc+ab3);
    a_read(h9,slot,0,arow,kb,Ah,Al);
    acc=mfma16(Ah,B0,acc); acc=mfma16(Al,B0,acc); acc=mfma16(Ah,B1,acc);
    a_read(h9,slot,1,arow,kb,Ah,Al);
    acc=mfma16(Ah,B2,acc); acc=mfma16(Al,B2,acc); acc=mfma16(Ah,B3,acc);
    return acc;
  };

  for(int t=0;t<T_SZ;t++){
    // ===== 9 LSTMs: read X(1..8)/slot0, write Y(11..18)/slot9; per-l barrier (R12-style) =====
    #pragma unroll
    for(int l=0;l<9;l++){
      const int slotA=(l==0)?0:l;       // fused input
      const int slotW=(l==0)?9:(10+l);  // raw output
      const char* Wl=Wmb + ((size_t)(l*12+t)*6)*16384;
      vf4 a0={0,0,0,0},a1={0,0,0,0};
      vi4 Ah,Al,Bh0,Bh1,Bl0,Bl1;
      // ks0
      Bh0=g16(Wl+b0); Bh1=g16(Wl+b1); Bl0=g16(Wl+16384+b0); Bl1=g16(Wl+16384+b1);
      a_read(h9,slotA,0,arow,kb,Ah,Al);
      a0=mfma16(Ah,Bh0,a0); a0=mfma16(Al,Bh0,a0); a0=mfma16(Ah,Bl0,a0);
      a1=mfma16(Ah,Bh1,a1); a1=mfma16(Al,Bh1,a1); a1=mfma16(Ah,Bl1,a1);
      // ks1
      Bh0=g16(Wl+2*16384+b0); Bh1=g16(Wl+2*16384+b1);
      Bl0=g16(Wl+3*16384+b0); Bl1=g16(Wl+3*16384+b1);
      a_read(h9,slotA,1,arow,kb,Ah,Al);
      a0=mfma16(Ah,Bh0,a0); a0=mfma16(Al,Bh0,a0); a0=mfma16(Ah,Bl0,a0);
      a1=mfma16(Ah,Bh1,a1); a1=mfma16(Al,Bh1,a1); a1=mfma16(Ah,Bl1,a1);
      // ks2: A = [x(16) | bias-1 | 0], pre-split frags from ws
      Bh0=g16(Wl+4*16384+b0); Bh1=g16(Wl+4*16384+b1);
      Bl0=g16(Wl+5*16384+b0); Bl1=g16(Wl+5*16384+b1);
      if(kb<2){
        const char* xp=Xfb + (size_t)(l*24 + t*2 + kb)*32;
        Ah=g16(xp); Al=g16(xp+16);
      } else if(kb==2){ Ah=(vi4){0x3F80,0,0,0}; Al=(vi4){0,0,0,0}; }
      else            { Ah=(vi4){0,0,0,0};     Al=(vi4){0,0,0,0}; }
      a0=mfma16(Ah,Bh0,a0); a0=mfma16(Al,Bh0,a0); a0=mfma16(Ah,Bl0,a0);
      a1=mfma16(Ah,Bh1,a1); a1=mfma16(Al,Bh1,a1); a1=mfma16(Ah,Bl1,a1);
      // nonlin: quad-transpose; thread owns (rowN, u0) and (rowN, u0+1)
      {
        float hh2[2],cc2[2];
        vf4 accs[2]={a0,a1};
        #pragma unroll
        for(int nt=0;nt<2;nt++){
          vf4 av=accs[nt];
          float v0=av[0],v1=av[1],v2=av[2],v3=av[3];
          auto sel=[&](int e)->float{ return e==0?v0:(e==1?v1:(e==2?v2:v3)); };
          float own=sel(qq);
          float r1=__shfl_xor(sel(qq^1),1);
          float r2=__shfl_xor(sel(qq^2),2);
          float r3=__shfl_xor(sel(qq^3),3);
          float gi=(qq==0)?own:((qq==1)?r1:((qq==2)?r2:r3));
          float gf=(qq==1)?own:((qq==0)?r1:((qq==3)?r2:r3));
          float gg=(qq==2)?own:((qq==3)?r1:((qq==0)?r2:r3));
          float go=(qq==3)?own:((qq==2)?r1:((qq==1)?r2:r3));
          float iv=sigm(gi),fv=sigm(gf),gv=tanh_f(gg),ov=sigm(go);
          float c2=fv*cst[l][nt]+iv*gv;
          cc2[nt]=c2; hh2[nt]=ov*tanh_f(c2);
        }
        cst[l][0]=cc2[0]; cst[l][1]=cc2[1];
        h9_w2(h9,slotW,rowN,u0,hh2[0],hh2[1]);
      }
      __syncthreads();   // per-l skew bound (R12-proven discipline); last one = b2
    }

    const bool dofuse=(t<T_SZ-1);
    vf4 g1,g2,g3,g4,g5,g6,g7,g8;   // fusion results held in regs across phS/phH (R12 pattern)
    // ===== window 1: phKQ (w0-3) CONCURRENT with f_ts+fusion-compute (w4-7) =====
    if(w4){
      vf4 aq=attn_gemm(Wab+0*16384, 9, (vf4){bQK,bQK,bQK,bQK});   // qk = h_ts@QKc + bqk
      #pragma unroll
      for(int rg=0;rg<4;rg++) qkf[(crow0+rg)*64+colw]=aq[rg];
    } else if(dofuse){
      vf4 facc=attn_gemm(Wab+3*16384, 9, (vf4){bf1v,bf1v,bf1v,bf1v}); // f_ts
      const char* Wc=Wab+4*16384;
      vi4 B0=g16(Wc+ab0),B1=g16(Wc+ab1),B2=g16(Wc+ab2),B3=g16(Wc+ab3);
      vi4 Ah,Al;
      g1=facc;g2=facc;g3=facc;g4=facc;g5=facc;g6=facc;g7=facc;g8=facc;
      #define FUSE(gn,slot) \
        a_read(h9,slot,0,arow,kb,Ah,Al); \
        gn=mfma16(Ah,B0,gn); gn=mfma16(Al,B0,gn); gn=mfma16(Ah,B1,gn); \
        a_read(h9,slot,1,arow,kb,Ah,Al); \
        gn=mfma16(Ah,B2,gn); gn=mfma16(Al,B2,gn); gn=mfma16(Ah,B3,gn);
      FUSE(g1,11) FUSE(g2,12) FUSE(g3,13) FUSE(g4,14)
      FUSE(g5,15) FUSE(g6,16) FUSE(g7,17) FUSE(g8,18)
      #undef FUSE
    }
    __syncthreads();   // b3: qk visible; fusion g's safely in regs
    // ===== phS: scores + softmax -> pbuf (dedicated buffer, no aliasing) =====
    if(tid<128){
      int rr=tid>>3, nn=tid&7;
      const char* hp=h9+(11+nn)*4096;
      float s=0.f;
      #pragma unroll
      for(int kbl=0;kbl<8;kbl++){
        int blk=kbl^(rr&7);
        const char* pp=hp+(rr*8+blk)*16;
        vi4 hv=*(const vi4*)pp;
        vi4 lv=*(const vi4*)(pp+2048);
        const float* qkp=qkf+rr*64+kbl*8;
        #pragma unroll
        for(int e=0;e<4;e++){
          unsigned hw=((const unsigned*)&hv)[e], lw=((const unsigned*)&lv)[e];
          float w0=__uint_as_float(hw<<16)+__uint_as_float(lw<<16);
          float w1=__uint_as_float(hw&0xffff0000u)+__uint_as_float(lw&0xffff0000u);
          s+=w0*qkp[e*2]+w1*qkp[e*2+1];
        }
      }
      float mx=s;
      mx=fmaxf(mx,__shfl_xor(mx,1));
      mx=fmaxf(mx,__shfl_xor(mx,2));
      mx=fmaxf(mx,__shfl_xor(mx,4));
      float e=__expf(s-mx);
      float sm=e;
      sm+=__shfl_xor(sm,1); sm+=__shfl_xor(sm,2); sm+=__shfl_xor(sm,4);
      pbuf[tid]=e/sm;
    }
    __syncthreads();   // b4: p visible; all qkf reads done
    // ===== phH: hbar -> region R (split-bf16), ALL 8 waves, 2 rows each (R12 pattern) =====
    {
      #pragma unroll
      for(int ri=0;ri<2;ri++){
        int row=w*2+ri;
        float sa=0.f;
        #pragma unroll
        for(int n=0;n<8;n++) sa+=pbuf[row*8+n]*h9_rd(h9,11+n,row,ln);
        h9_w1(h9,10,row,ln,sa);
      }
    }
    __syncthreads();   // b5: hbar visible
    // ===== phC+phB (w0-3) -> slot0 ; CONCURRENT X-writes from g-regs (w4-7) =====
    if(w4){
      vf4 acA=attn_gemm(Wab+1*16384, 10, (vf4){bF,bF,bF,bF});
      acA=attn_gemm(Wab+2*16384, 9, acA);
      #pragma unroll
      for(int rg=0;rg<4;rg++) h9_w1(h9,0,crow0+rg,colw,fmaxf(acA[rg],0.f));
    } else if(dofuse){
      #pragma unroll
      for(int rg=0;rg<4;rg++){
        h9_w1(h9,1,crow0+rg,colw,fmaxf(g1[rg],0.f));
        h9_w1(h9,2,crow0+rg,colw,fmaxf(g2[rg],0.f));
        h9_w1(h9,3,crow0+rg,colw,fmaxf(g3[rg],0.f));
        h9_w1(h9,4,crow0+rg,colw,fmaxf(g4[rg],0.f));
        h9_w1(h9,5,crow0+rg,colw,fmaxf(g5[rg],0.f));
        h9_w1(h9,6,crow0+rg,colw,fmaxf(g6[rg],0.f));
        h9_w1(h9,7,crow0+rg,colw,fmaxf(g7[rg],0.f));
        h9_w1(h9,8,crow0+rg,colw,fmaxf(g8[rg],0.f));
      }
    }
    __syncthreads();   // b6: slot0 + X visible for next t / MLP
  }

  // ===== final MLP from slot0 (h_tsa) =====
  {
    float* hid=(float*)(h9+10*4096);   // region R dead
    int rr=tid>>5, ii=tid&31;
    float h=P.m1b[ii];
    for(int k=0;k<64;k++) h+=h9_rd(h9,0,rr,k)*P.m1w[(size_t)ii*64+k];
    hid[rr*32+ii]=fmaxf(h,0.f);
    __syncthreads();
    if(tid<R_WG){
      float s=P.m2b[0];
      for(int i=0;i<32;i++) s+=hid[tid*32+i]*P.m2w[i];
      P.out[r0+tid]=s;
    }
  }
}

// ---- prep: LSTM weight chunks, split-bf16, frag layout; bias folded at k=80 ----
__global__ void prep_wm(const float* eW, const float* eU, const float* e2W, const float* e2U,
                        const float* emb_w, const float* eb_ih, const float* eb_hh,
                        const float* e2b_ih, const float* e2b_hh, const float* emb_b,
                        unsigned short* dst){
  int id=blockIdx.x*256+threadIdx.x;
  if(id>=108*3*16*64) return;
  int lane=id&63;
  int q=id>>6;
  int wnt=q&15;
  int q2=q>>4;
  int ks=q2%3;
  int lt=q2/3;
  int LL=lt/12, t=lt%12;
  int c15=lane&15;
  int u=(wnt>>2)*16+(c15>>2)*4+(wnt&3);
  int gt=c15&3;
  int jg=gt*64+u;
  const float* Whh=(LL==0)? eU+((size_t)t*256+jg)*64 : e2U+(((size_t)(LL-1)*12+t)*256+jg)*64;
  const float* Wih=(LL==0)? eW+((size_t)t*256+jg)*32 : e2W+(((size_t)(LL-1)*12+t)*256+jg)*32;
  float bsum;
  {
    float bi=(LL==0)? eb_ih[t*256+jg] : e2b_ih[((LL-1)*12+t)*256+jg];
    float bh=(LL==0)? eb_hh[t*256+jg] : e2b_hh[((LL-1)*12+t)*256+jg];
    float s=bi+bh;
    for(int i=0;i<32;i++) s+=Wih[i]*emb_b[i];
    bsum=s;
  }
  #pragma unroll
  for(int j=0;j<8;j++){
    int k=ks*32+(lane>>4)*8+j;
    float v;
    if(k<64) v=Whh[k];
    else if(k<80){
      int kx=k-64; float s=0.f;
      for(int i=0;i<32;i++) s+=Wih[i]*emb_w[i*16+kx];
      v=s;
    } else if(k==80) v=bsum;
    else v=0.f;
    unsigned short hi=bf_hi(v), lo=bf_hi(v-bf_f(hi));
    size_t base=((size_t)lt*6+ks*2)*8192 + ((size_t)wnt*64+lane)*8 + j;
    dst[base]=hi;
    dst[base+8192]=lo;
  }
}

// ---- prep: 5 attention/fusion chunks [colblk][ks][split][lane][8], + Fbp + bqk ----
// cidx: 0=QKc(0.125*Qw.T@Kw), 1=VFc(FwA@Vw), 2=FBc, 3=F1Bc, 4=F1Ac
__global__ void prep_attw(const float* Qw, const float* Qb, const float* Kw,
                          const float* Vw, const float* Vb,
                          const float* Fw, const float* Fb, const float* f1w,
                          unsigned short* dst, float* Fbp, float* bqk){
  int id=blockIdx.x*256+threadIdx.x;
  if(id<5120){
    int cidx=id>>10;
    int rem=id&1023;
    int block=rem>>6;
    int lane=rem&63;
    int ks=(block>>1)&1, s=block&1;
    int col=(block>>2)*16+(lane&15);
    #pragma unroll
    for(int j=0;j<8;j++){
      int k=ks*32+(lane>>4)*8+j;
      float v;
      if(cidx==0){ float sv=0.f; for(int m=0;m<64;m++) sv+=Qw[m*64+k]*Kw[m*64+col]; v=sv*0.125f; }
      else if(cidx==1){ float sv=0.f; for(int m=0;m<64;m++) sv+=Fw[col*128+m]*Vw[m*64+k]; v=sv; }
      else if(cidx==2) v=Fw[col*128+64+k];
      else if(cidx==3) v=f1w[col*128+64+k];
      else             v=f1w[col*128+k];
      unsigned short hi=bf_hi(v);
      dst[(size_t)cidx*8192 + ((size_t)block*64+lane)*8 + j] = (s==0)? hi : bf_hi(v-bf_f(hi));
    }
  } else if(id<5184){
    int u=id-5120;
    float s=Fb[u];
    for(int m=0;m<64;m++) s+=Fw[u*128+m]*Vb[m];
    Fbp[u]=s;
  } else if(id<5248){
    int m=id-5184;
    float s=0.f;
    for(int u=0;u<64;u++) s+=Qb[u]*Kw[u*64+m];
    bqk[m]=s*0.125f;
  }
}

// ---- prep: x A-fragments pre-split: [b][src 0..8][t][kb]{hi 16B, lo 16B} ----
__global__ void prep_xf(const float* ts, const float* gts, unsigned short* xf){
  int id=blockIdx.x*256+threadIdx.x;
  if(id>=8192*9*24) return;
  int kb=id&1;
  int t=(id>>1)%12;
  int q=id/24;
  int src=q%9;
  int b=q/9;
  const float* s=(src==0)? ts+(size_t)b*192+(size_t)t*16+kb*8
                         : gts+(size_t)b*1536+(size_t)(src-1)*192+(size_t)t*16+kb*8;
  unsigned short* d=xf+(size_t)id*16;
  #pragma unroll
  for(int j=0;j<8;j++){
    float f=s[j];
    unsigned short hi=bf_hi(f);
    d[j]=hi;
    d[8+j]=bf_hi(f-bf_f(hi));
  }
}

extern "C" void kernel_launch(void* const* d_in, const int* in_sizes, int n_in,
                              void* d_out, int out_size, void* d_ws, size_t ws_size,
                              hipStream_t stream){
  const float* ts      =(const float*)d_in[0];
  const float* gts     =(const float*)d_in[1];
  const float* emb_w   =(const float*)d_in[2];
  const float* emb_b   =(const float*)d_in[3];
  const float* attQ_w  =(const float*)d_in[4];
  const float* attQ_b  =(const float*)d_in[5];
  const float* attK_w  =(const float*)d_in[6];
  // d_in[7] attK_b: softmax-invariant, unused
  const float* attV_w  =(const float*)d_in[8];
  const float* attV_b  =(const float*)d_in[9];
  const float* attF_w  =(const float*)d_in[10];
  const float* attF_b  =(const float*)d_in[11];
  const float* fuse1_w =(const float*)d_in[12];
  const float* fuse1_b =(const float*)d_in[13];
  const float* enc_Wih =(const float*)d_in[14];
  const float* enc_Whh =(const float*)d_in[15];
  const float* enc_bih =(const float*)d_in[16];
  const float* enc_bhh =(const float*)d_in[17];
  const float* enc2_Wih=(const float*)d_in[18];
  const float* enc2_Whh=(const float*)d_in[19];
  const float* enc2_bih=(const float*)d_in[20];
  const float* enc2_bhh=(const float*)d_in[21];
  const float* mlp1_w  =(const float*)d_in[22];
  const float* mlp1_b  =(const float*)d_in[23];
  const float* mlp2_w  =(const float*)d_in[24];
  const float* mlp2_b  =(const float*)d_in[25];

  char* ws=(char*)d_ws;
  size_t off=0;
  unsigned short* Wm=(unsigned short*)(ws+off); off+=(size_t)108*6*8192*2;
  unsigned short* Wa=(unsigned short*)(ws+off); off+=(size_t)5*8192*2;
  float* Fbp=(float*)(ws+off); off+=64*4;
  float* bqk=(float*)(ws+off); off+=64*4;
  unsigned short* Xf=(unsigned short*)(ws+off); off+=(size_t)8192*9*24*16*2;

  prep_wm<<<(108*3*16*64+255)/256,256,0,stream>>>(enc_Wih,enc_Whh,enc2_Wih,enc2_Whh,emb_w,
                                                  enc_bih,enc_bhh,enc2_bih,enc2_bhh,emb_b,Wm);
  prep_attw<<<21,256,0,stream>>>(attQ_w,attQ_b,attK_w,attV_w,attV_b,attF_w,attF_b,fuse1_w,
                                 Wa,Fbp,bqk);
  prep_xf<<<(8192*9*24+255)/256,256,0,stream>>>(ts,gts,Xf);

  Ptrs P;
  P.Wm=Wm; P.Wa=Wa; P.Xf=Xf;
  P.Fbp=Fbp; P.bqk=bqk; P.f1b=fuse1_b;
  P.m1w=mlp1_w; P.m1b=mlp1_b; P.m2w=mlp2_w; P.m2b=mlp2_b;
  P.out=(float*)d_out;

  fused_kernel<<<NWG,NTHR,0,stream>>>(P);
}

// Round 15
// 501.938 us; speedup vs baseline: 1.3304x; 1.1679x over previous
//
#include <hip/hip_runtime.h>

#define T_SZ 12
#define R_WG 16
#define NTHR 512
#define NWG  512   // 8192/16

typedef float  vf4 __attribute__((ext_vector_type(4)));
typedef int    vi4 __attribute__((ext_vector_type(4)));
typedef __bf16 vbf8 __attribute__((ext_vector_type(8)));

__device__ __forceinline__ float sigm(float x){ return 1.f/(1.f+__expf(-x)); }
// tanh(x) = 1 - 2/(e^{2x}+1): algebraically exact, no sign-select (saves ~3 ops)
__device__ __forceinline__ float tanh_f(float x){
  float e=__expf(2.f*x); return 1.f - 2.f/(e+1.f);
}
__device__ __forceinline__ unsigned short bf_hi(float f){
  unsigned int b=__float_as_uint(f);
  return (unsigned short)((b + 0x7fffu + ((b>>16)&1u))>>16);
}
__device__ __forceinline__ float bf_f(unsigned short h){
  return __uint_as_float(((unsigned int)h)<<16);
}
__device__ __forceinline__ vf4 mfma16(vi4 a, vi4 b, vf4 c){
  return __builtin_amdgcn_mfma_f32_16x16x32_bf16(
      __builtin_bit_cast(vbf8,a), __builtin_bit_cast(vbf8,b), c, 0, 0, 0);
}
__device__ __forceinline__ vi4 g16(const char* p){ return *(const vi4*)p; }

// split-bf16 h slots: slot*4096 + [split +2048] + (row*8 + ((k>>3)^(row&7)))*16 + (k&7)*2
// slots: 0=h_tsa, 1..8=X fused nodes, 9=h_ts, 10=R (qk fp32 / hbar), 11..18=Y raw nodes
__device__ __forceinline__ void a_read(const char* h9,int slot,int ks,int arow,int kb,vi4& Ah,vi4& Al){
  int blk=((ks<<2)+kb)^(arow&7);
  const char* p=h9+slot*4096+(arow*8+blk)*16;
  Ah=*(const vi4*)p; Al=*(const vi4*)(p+2048);
}
__device__ __forceinline__ void h9_w1(char* h9,int slot,int row,int k,float v){
  int off=slot*4096+(row*8+((k>>3)^(row&7)))*16+(k&7)*2;
  unsigned short hi=bf_hi(v);
  *(unsigned short*)(h9+off)=hi;
  *(unsigned short*)(h9+off+2048)=bf_hi(v-bf_f(hi));
}
__device__ __forceinline__ void h9_w2(char* h9,int slot,int row,int k0,float v0,float v1){
  int off=slot*4096+(row*8+((k0>>3)^(row&7)))*16+(k0&7)*2;
  unsigned short h0=bf_hi(v0),h1=bf_hi(v1);
  *(unsigned*)(h9+off)=(unsigned)h0|((unsigned)h1<<16);
  *(unsigned*)(h9+off+2048)=(unsigned)bf_hi(v0-bf_f(h0))|((unsigned)bf_hi(v1-bf_f(h1))<<16);
}
// write 4 consecutive k (k0 multiple of 4, same 8-k block): packed 8B hi + 8B lo
__device__ __forceinline__ void h9_w4c(char* h9,int slot,int row,int k0,vf4 v){
  int off=slot*4096+(row*8+((k0>>3)^(row&7)))*16+(k0&7)*2;
  unsigned short h0=bf_hi(v[0]),h1=bf_hi(v[1]),h2=bf_hi(v[2]),h3=bf_hi(v[3]);
  uint2 hv; hv.x=(unsigned)h0|((unsigned)h1<<16); hv.y=(unsigned)h2|((unsigned)h3<<16);
  *(uint2*)(h9+off)=hv;
  uint2 lv;
  lv.x=(unsigned)bf_hi(v[0]-bf_f(h0))|((unsigned)bf_hi(v[1]-bf_f(h1))<<16);
  lv.y=(unsigned)bf_hi(v[2]-bf_f(h2))|((unsigned)bf_hi(v[3]-bf_f(h3))<<16);
  *(uint2*)(h9+off+2048)=lv;
}
__device__ __forceinline__ float h9_rd(const char* h9,int slot,int row,int k){
  int off=slot*4096+(row*8+((k>>3)^(row&7)))*16+(k&7)*2;
  return bf_f(*(const unsigned short*)(h9+off))+bf_f(*(const unsigned short*)(h9+off+2048));
}

struct Ptrs {
  const unsigned short* Wm; const unsigned short* Wa; const unsigned short* Xf;
  const float* Fbp; const float* bqk; const float* f1b;
  const float* m1w; const float* m1b; const float* m2w; const float* m2b;
  float* out;
};

__global__ __launch_bounds__(NTHR,4) void fused_kernel(Ptrs P){
  __shared__ __align__(16) char  h9[77824];     // 19 slots x 4KB
  __shared__ __align__(16) float pbuf[128];

  const int tid=threadIdx.x;
  const int r0=blockIdx.x*R_WG;
  const int w=tid>>6, ln=tid&63;
  const bool w4=(w<4);
  const int arow=ln&15, kb=ln>>4;
  const int rowL=ln&15;                                    // batch row owned (swapped C: col=lane&15)
  const int uA=((2*w)>>2)*16 + (ln>>4)*4 + ((2*w)&3);      // LSTM u for a0 (a1 = uA+1)
  const int ub=(w&3)*16 + (ln>>4)*4;                       // attn u base (4 consecutive)
  const char* Wmb=(const char*)P.Wm;
  const char* Wab=(const char*)P.Wa;
  const char* Xfb=(const char*)P.Xf + (size_t)(r0+arow)*9*24*32;
  float* qkf=(float*)(h9+10*4096);                         // region R as fp32 qk
  const int b0=((2*w+0)*64+ln)*16, b1=((2*w+1)*64+ln)*16;
  const int ab0=(((w&3)*4+0)*64+ln)*16, ab1=(((w&3)*4+1)*64+ln)*16;
  const int ab2=(((w&3)*4+2)*64+ln)*16, ab3=(((w&3)*4+3)*64+ln)*16;

  const vf4 bqk4=*(const vf4*)(P.bqk+ub);
  const vf4 bF4 =*(const vf4*)(P.Fbp+ub);
  const vf4 bf14=*(const vf4*)(P.f1b+ub);

  float cst[9][2];
  #pragma unroll
  for(int l=0;l<9;l++){ cst[l][0]=0.f; cst[l][1]=0.f; }

  for(int i=tid;i<77824/16;i+=NTHR) ((vi4*)h9)[i]=(vi4){0,0,0,0};
  __syncthreads();   // zeros visible

  // swapped attn GEMM: A = weight frag, B = h frag; C[u-in-block][batch row]
  auto attn_gemm=[&](const char* Wc,int slot,vf4 acc)->vf4{
    vi4 Bh,Bl;
    vi4 W0=g16(Wc+ab0),W1=g16(Wc+ab1),W2=g16(Wc+ab2),W3=g16(Wc+ab3);
    a_read(h9,slot,0,arow,kb,Bh,Bl);
    acc=mfma16(W0,Bh,acc); acc=mfma16(W0,Bl,acc); acc=mfma16(W1,Bh,acc);
    a_read(h9,slot,1,arow,kb,Bh,Bl);
    acc=mfma16(W2,Bh,acc); acc=mfma16(W2,Bl,acc); acc=mfma16(W3,Bh,acc);
    return acc;
  };

  for(int t=0;t<T_SZ;t++){
    // ===== 9 LSTMs (swapped operands): read X(1..8)/slot0, write Y(11..18)/slot9 =====
    #pragma unroll
    for(int l=0;l<9;l++){
      const int slotA=(l==0)?0:l;       // fused input
      const int slotW=(l==0)?9:(10+l);  // raw output
      const char* Wl=Wmb + ((size_t)(l*12+t)*6)*16384;
      vf4 a0={0,0,0,0},a1={0,0,0,0};
      vi4 Bh,Bl,Wh0,Wh1,Wl0,Wl1;
      // ks0
      Wh0=g16(Wl+b0); Wh1=g16(Wl+b1); Wl0=g16(Wl+16384+b0); Wl1=g16(Wl+16384+b1);
      a_read(h9,slotA,0,arow,kb,Bh,Bl);
      a0=mfma16(Wh0,Bh,a0); a0=mfma16(Wh0,Bl,a0); a0=mfma16(Wl0,Bh,a0);
      a1=mfma16(Wh1,Bh,a1); a1=mfma16(Wh1,Bl,a1); a1=mfma16(Wl1,Bh,a1);
      // ks1
      Wh0=g16(Wl+2*16384+b0); Wh1=g16(Wl+2*16384+b1);
      Wl0=g16(Wl+3*16384+b0); Wl1=g16(Wl+3*16384+b1);
      a_read(h9,slotA,1,arow,kb,Bh,Bl);
      a0=mfma16(Wh0,Bh,a0); a0=mfma16(Wh0,Bl,a0); a0=mfma16(Wl0,Bh,a0);
      a1=mfma16(Wh1,Bh,a1); a1=mfma16(Wh1,Bl,a1); a1=mfma16(Wl1,Bh,a1);
      // ks2: B = [x(16) | bias-1 | 0], pre-split frags from ws
      Wh0=g16(Wl+4*16384+b0); Wh1=g16(Wl+4*16384+b1);
      Wl0=g16(Wl+5*16384+b0); Wl1=g16(Wl+5*16384+b1);
      if(kb<2){
        const char* xp=Xfb + (size_t)(l*24 + t*2 + kb)*32;
        Bh=g16(xp); Bl=g16(xp+16);
      } else if(kb==2){ Bh=(vi4){0x3F80,0,0,0}; Bl=(vi4){0,0,0,0}; }
      else            { Bh=(vi4){0,0,0,0};     Bl=(vi4){0,0,0,0}; }
      a0=mfma16(Wh0,Bh,a0); a0=mfma16(Wh0,Bl,a0); a0=mfma16(Wl0,Bh,a0);
      a1=mfma16(Wh1,Bh,a1); a1=mfma16(Wh1,Bl,a1); a1=mfma16(Wl1,Bh,a1);
      // nonlin: gates land directly in acc[0..3] (i,f,g,o) — no transpose
      {
        float iv=sigm(a0[0]), fv=sigm(a0[1]), gv=tanh_f(a0[2]), ov=sigm(a0[3]);
        float c20=fv*cst[l][0]+iv*gv;
        cst[l][0]=c20;
        float h0v=ov*tanh_f(c20);
        iv=sigm(a1[0]); fv=sigm(a1[1]); gv=tanh_f(a1[2]); ov=sigm(a1[3]);
        float c21=fv*cst[l][1]+iv*gv;
        cst[l][1]=c21;
        float h1v=ov*tanh_f(c21);
        h9_w2(h9,slotW,rowL,uA,h0v,h1v);
      }
      __syncthreads();   // per-l skew bound (replay-stable R14 discipline)
    }

    const bool dofuse=(t<T_SZ-1);
    vf4 g1,g2,g3,g4,g5,g6,g7,g8;   // fusion results held in regs across phS/phH
    // ===== window 1: phKQ (w0-3) CONCURRENT with f_ts+fusion-compute (w4-7) =====
    if(w4){
      vf4 aq=attn_gemm(Wab+0*16384, 9, bqk4);   // qk = h_ts@QKc + bqk, C[u][row]
      *(vf4*)(qkf + rowL*64 + ub) = aq;
    } else if(dofuse){
      vf4 facc=attn_gemm(Wab+3*16384, 9, bf14); // f_ts
      const char* Wc=Wab+4*16384;
      vi4 W0=g16(Wc+ab0),W1=g16(Wc+ab1),W2=g16(Wc+ab2),W3=g16(Wc+ab3);
      vi4 Bh,Bl;
      g1=facc;g2=facc;g3=facc;g4=facc;g5=facc;g6=facc;g7=facc;g8=facc;
      #define FUSE(gn,slot) \
        a_read(h9,slot,0,arow,kb,Bh,Bl); \
        gn=mfma16(W0,Bh,gn); gn=mfma16(W0,Bl,gn); gn=mfma16(W1,Bh,gn); \
        a_read(h9,slot,1,arow,kb,Bh,Bl); \
        gn=mfma16(W2,Bh,gn); gn=mfma16(W2,Bl,gn); gn=mfma16(W3,Bh,gn);
      FUSE(g1,11) FUSE(g2,12) FUSE(g3,13) FUSE(g4,14)
      FUSE(g5,15) FUSE(g6,16) FUSE(g7,17) FUSE(g8,18)
      #undef FUSE
    }
    __syncthreads();   // b3: qk visible; fusion g's safely in regs
    // ===== phS: scores + softmax -> pbuf =====
    if(tid<128){
      int rr=tid>>3, nn=tid&7;
      const char* hp=h9+(11+nn)*4096;
      float s=0.f;
      #pragma unroll
      for(int kbl=0;kbl<8;kbl++){
        int blk=kbl^(rr&7);
        const char* pp=hp+(rr*8+blk)*16;
        vi4 hv=*(const vi4*)pp;
        vi4 lv=*(const vi4*)(pp+2048);
        const float* qkp=qkf+rr*64+kbl*8;
        #pragma unroll
        for(int e=0;e<4;e++){
          unsigned hw=((const unsigned*)&hv)[e], lw=((const unsigned*)&lv)[e];
          float w0=__uint_as_float(hw<<16)+__uint_as_float(lw<<16);
          float w1=__uint_as_float(hw&0xffff0000u)+__uint_as_float(lw&0xffff0000u);
          s+=w0*qkp[e*2]+w1*qkp[e*2+1];
        }
      }
      float mx=s;
      mx=fmaxf(mx,__shfl_xor(mx,1));
      mx=fmaxf(mx,__shfl_xor(mx,2));
      mx=fmaxf(mx,__shfl_xor(mx,4));
      float e=__expf(s-mx);
      float sm=e;
      sm+=__shfl_xor(sm,1); sm+=__shfl_xor(sm,2); sm+=__shfl_xor(sm,4);
      pbuf[tid]=e/sm;
    }
    __syncthreads();   // b4: p visible; all qkf reads done
    // ===== phH: hbar -> region R (split-bf16), ALL 8 waves, 2 rows each =====
    {
      #pragma unroll
      for(int ri=0;ri<2;ri++){
        int row=w*2+ri;
        float sa=0.f;
        #pragma unroll
        for(int n=0;n<8;n++) sa+=pbuf[row*8+n]*h9_rd(h9,11+n,row,ln);
        h9_w1(h9,10,row,ln,sa);
      }
    }
    __syncthreads();   // b5: hbar visible
    // ===== phC+phB (w0-3) -> slot0 ; CONCURRENT X-writes from g-regs (w4-7) =====
    if(w4){
      vf4 acA=attn_gemm(Wab+1*16384, 10, bF4);
      acA=attn_gemm(Wab+2*16384, 9, acA);
      acA[0]=fmaxf(acA[0],0.f); acA[1]=fmaxf(acA[1],0.f);
      acA[2]=fmaxf(acA[2],0.f); acA[3]=fmaxf(acA[3],0.f);
      h9_w4c(h9,0,rowL,ub,acA);
    } else if(dofuse){
      #define WRX(gn,slot) \
        gn[0]=fmaxf(gn[0],0.f); gn[1]=fmaxf(gn[1],0.f); \
        gn[2]=fmaxf(gn[2],0.f); gn[3]=fmaxf(gn[3],0.f); \
        h9_w4c(h9,slot,rowL,ub,gn);
      WRX(g1,1) WRX(g2,2) WRX(g3,3) WRX(g4,4)
      WRX(g5,5) WRX(g6,6) WRX(g7,7) WRX(g8,8)
      #undef WRX
    }
    __syncthreads();   // b6: slot0 + X visible for next t / MLP
  }

  // ===== final MLP from slot0 (h_tsa) =====
  {
    float* hid=(float*)(h9+10*4096);   // region R dead
    int rr=tid>>5, ii=tid&31;
    float h=P.m1b[ii];
    for(int k=0;k<64;k++) h+=h9_rd(h9,0,rr,k)*P.m1w[(size_t)ii*64+k];
    hid[rr*32+ii]=fmaxf(h,0.f);
    __syncthreads();
    if(tid<R_WG){
      float s=P.m2b[0];
      for(int i=0;i<32;i++) s+=hid[tid*32+i]*P.m2w[i];
      P.out[r0+tid]=s;
    }
  }
}

// ---- prep: LSTM weight chunks, split-bf16, frag layout; bias folded at k=80 ----
__global__ void prep_wm(const float* eW, const float* eU, const float* e2W, const float* e2U,
                        const float* emb_w, const float* eb_ih, const float* eb_hh,
                        const float* e2b_ih, const float* e2b_hh, const float* emb_b,
                        unsigned short* dst){
  int id=blockIdx.x*256+threadIdx.x;
  if(id>=108*3*16*64) return;
  int lane=id&63;
  int q=id>>6;
  int wnt=q&15;
  int q2=q>>4;
  int ks=q2%3;
  int lt=q2/3;
  int LL=lt/12, t=lt%12;
  int c15=lane&15;
  int u=(wnt>>2)*16+(c15>>2)*4+(wnt&3);
  int gt=c15&3;
  int jg=gt*64+u;
  const float* Whh=(LL==0)? eU+((size_t)t*256+jg)*64 : e2U+(((size_t)(LL-1)*12+t)*256+jg)*64;
  const float* Wih=(LL==0)? eW+((size_t)t*256+jg)*32 : e2W+(((size_t)(LL-1)*12+t)*256+jg)*32;
  float bsum;
  {
    float bi=(LL==0)? eb_ih[t*256+jg] : e2b_ih[((LL-1)*12+t)*256+jg];
    float bh=(LL==0)? eb_hh[t*256+jg] : e2b_hh[((LL-1)*12+t)*256+jg];
    float s=bi+bh;
    for(int i=0;i<32;i++) s+=Wih[i]*emb_b[i];
    bsum=s;
  }
  #pragma unroll
  for(int j=0;j<8;j++){
    int k=ks*32+(lane>>4)*8+j;
    float v;
    if(k<64) v=Whh[k];
    else if(k<80){
      int kx=k-64; float s=0.f;
      for(int i=0;i<32;i++) s+=Wih[i]*emb_w[i*16+kx];
      v=s;
    } else if(k==80) v=bsum;
    else v=0.f;
    unsigned short hi=bf_hi(v), lo=bf_hi(v-bf_f(hi));
    size_t base=((size_t)lt*6+ks*2)*8192 + ((size_t)wnt*64+lane)*8 + j;
    dst[base]=hi;
    dst[base+8192]=lo;
  }
}

// ---- prep: 5 attention/fusion chunks [colblk][ks][split][lane][8], + Fbp + bqk ----
// cidx: 0=QKc(0.125*Qw.T@Kw), 1=VFc(FwA@Vw), 2=FBc, 3=F1Bc, 4=F1Ac
__global__ void prep_attw(const float* Qw, const float* Qb, const float* Kw,
                          const float* Vw, const float* Vb,
                          const float* Fw, const float* Fb, const float* f1w,
                          unsigned short* dst, float* Fbp, float* bqk){
  int id=blockIdx.x*256+threadIdx.x;
  if(id<5120){
    int cidx=id>>10;
    int rem=id&1023;
    int block=rem>>6;
    int lane=rem&63;
    int ks=(block>>1)&1, s=block&1;
    int col=(block>>2)*16+(lane&15);
    #pragma unroll
    for(int j=0;j<8;j++){
      int k=ks*32+(lane>>4)*8+j;
      float v;
      if(cidx==0){ float sv=0.f; for(int m=0;m<64;m++) sv+=Qw[m*64+k]*Kw[m*64+col]; v=sv*0.125f; }
      else if(cidx==1){ float sv=0.f; for(int m=0;m<64;m++) sv+=Fw[col*128+m]*Vw[m*64+k]; v=sv; }
      else if(cidx==2) v=Fw[col*128+64+k];
      else if(cidx==3) v=f1w[col*128+64+k];
      else             v=f1w[col*128+k];
      unsigned short hi=bf_hi(v);
      dst[(size_t)cidx*8192 + ((size_t)block*64+lane)*8 + j] = (s==0)? hi : bf_hi(v-bf_f(hi));
    }
  } else if(id<5184){
    int u=id-5120;
    float s=Fb[u];
    for(int m=0;m<64;m++) s+=Fw[u*128+m]*Vb[m];
    Fbp[u]=s;
  } else if(id<5248){
    int m=id-5184;
    float s=0.f;
    for(int u=0;u<64;u++) s+=Qb[u]*Kw[u*64+m];
    bqk[m]=s*0.125f;
  }
}

// ---- prep: x A-fragments pre-split: [b][src 0..8][t][kb]{hi 16B, lo 16B} ----
__global__ void prep_xf(const float* ts, const float* gts, unsigned short* xf){
  int id=blockIdx.x*256+threadIdx.x;
  if(id>=8192*9*24) return;
  int kb=id&1;
  int t=(id>>1)%12;
  int q=id/24;
  int src=q%9;
  int b=q/9;
  const float* s=(src==0)? ts+(size_t)b*192+(size_t)t*16+kb*8
                         : gts+(size_t)b*1536+(size_t)(src-1)*192+(size_t)t*16+kb*8;
  unsigned short* d=xf+(size_t)id*16;
  #pragma unroll
  for(int j=0;j<8;j++){
    float f=s[j];
    unsigned short hi=bf_hi(f);
    d[j]=hi;
    d[8+j]=bf_hi(f-bf_f(hi));
  }
}

extern "C" void kernel_launch(void* const* d_in, const int* in_sizes, int n_in,
                              void* d_out, int out_size, void* d_ws, size_t ws_size,
                              hipStream_t stream){
  const float* ts      =(const float*)d_in[0];
  const float* gts     =(const float*)d_in[1];
  const float* emb_w   =(const float*)d_in[2];
  const float* emb_b   =(const float*)d_in[3];
  const float* attQ_w  =(const float*)d_in[4];
  const float* attQ_b  =(const float*)d_in[5];
  const float* attK_w  =(const float*)d_in[6];
  // d_in[7] attK_b: softmax-invariant, unused
  const float* attV_w  =(const float*)d_in[8];
  const float* attV_b  =(const float*)d_in[9];
  const float* attF_w  =(const float*)d_in[10];
  const float* attF_b  =(const float*)d_in[11];
  const float* fuse1_w =(const float*)d_in[12];
  const float* fuse1_b =(const float*)d_in[13];
  const float* enc_Wih =(const float*)d_in[14];
  const float* enc_Whh =(const float*)d_in[15];
  const float* enc_bih =(const float*)d_in[16];
  const float* enc_bhh =(const float*)d_in[17];
  const float* enc2_Wih=(const float*)d_in[18];
  const float* enc2_Whh=(const float*)d_in[19];
  const float* enc2_bih=(const float*)d_in[20];
  const float* enc2_bhh=(const float*)d_in[21];
  const float* mlp1_w  =(const float*)d_in[22];
  const float* mlp1_b  =(const float*)d_in[23];
  const float* mlp2_w  =(const float*)d_in[24];
  const float* mlp2_b  =(const float*)d_in[25];

  char* ws=(char*)d_ws;
  size_t off=0;
  unsigned short* Wm=(unsigned short*)(ws+off); off+=(size_t)108*6*8192*2;
  unsigned short* Wa=(unsigned short*)(ws+off); off+=(size_t)5*8192*2;
  float* Fbp=(float*)(ws+off); off+=64*4;
  float* bqk=(float*)(ws+off); off+=64*4;
  unsigned short* Xf=(unsigned short*)(ws+off); off+=(size_t)8192*9*24*16*2;

  prep_wm<<<(108*3*16*64+255)/256,256,0,stream>>>(enc_Wih,enc_Whh,enc2_Wih,enc2_Whh,emb_w,
                                                  enc_bih,enc_bhh,enc2_bih,enc2_bhh,emb_b,Wm);
  prep_attw<<<21,256,0,stream>>>(attQ_w,attQ_b,attK_w,attV_w,attV_b,attF_w,attF_b,fuse1_w,
                                 Wa,Fbp,bqk);
  prep_xf<<<(8192*9*24+255)/256,256,0,stream>>>(ts,gts,Xf);

  Ptrs P;
  P.Wm=Wm; P.Wa=Wa; P.Xf=Xf;
  P.Fbp=Fbp; P.bqk=bqk; P.f1b=fuse1_b;
  P.m1w=mlp1_w; P.m1b=mlp1_b; P.m2w=mlp2_w; P.m2b=mlp2_b;
  P.out=(float*)d_out;

  fused_kernel<<<NWG,NTHR,0,stream>>>(P);
}

// Round 16
// 442.397 us; speedup vs baseline: 1.5094x; 1.1346x over previous
//
#include <hip/hip_runtime.h>

#define T_SZ 12
#define R_WG 16
#define NTHR 512
#define NWG  512   // 8192/16

typedef float  vf4 __attribute__((ext_vector_type(4)));
typedef int    vi4 __attribute__((ext_vector_type(4)));
typedef __bf16 vbf8 __attribute__((ext_vector_type(8)));

__device__ __forceinline__ float sigm(float x){ return 1.f/(1.f+__expf(-x)); }
__device__ __forceinline__ float tanh_f(float x){
  float e=__expf(2.f*x); return 1.f - 2.f/(e+1.f);
}
__device__ __forceinline__ unsigned short bf_hi(float f){
  unsigned int b=__float_as_uint(f);
  return (unsigned short)((b + 0x7fffu + ((b>>16)&1u))>>16);
}
__device__ __forceinline__ float bf_f(unsigned short h){
  return __uint_as_float(((unsigned int)h)<<16);
}
__device__ __forceinline__ vf4 mfma16(vi4 a, vi4 b, vf4 c){
  return __builtin_amdgcn_mfma_f32_16x16x32_bf16(
      __builtin_bit_cast(vbf8,a), __builtin_bit_cast(vbf8,b), c, 0, 0, 0);
}
__device__ __forceinline__ vi4 g16(const char* p){ return *(const vi4*)p; }

// split-bf16 h slots: slot*4096 + [split +2048] + (row*8 + ((k>>3)^(row&7)))*16 + (k&7)*2
// slots: 0=h_tsa, 1..8=X fused nodes, 9=h_ts, 10=R (qk fp32 / hbar), 11..18=Y raw nodes
__device__ __forceinline__ void a_read(const char* h9,int slot,int ks,int arow,int kb,vi4& Ah,vi4& Al){
  int blk=((ks<<2)+kb)^(arow&7);
  const char* p=h9+slot*4096+(arow*8+blk)*16;
  Ah=*(const vi4*)p; Al=*(const vi4*)(p+2048);
}
__device__ __forceinline__ void h9_w1(char* h9,int slot,int row,int k,float v){
  int off=slot*4096+(row*8+((k>>3)^(row&7)))*16+(k&7)*2;
  unsigned short hi=bf_hi(v);
  *(unsigned short*)(h9+off)=hi;
  *(unsigned short*)(h9+off+2048)=bf_hi(v-bf_f(hi));
}
__device__ __forceinline__ void h9_w2(char* h9,int slot,int row,int k0,float v0,float v1){
  int off=slot*4096+(row*8+((k0>>3)^(row&7)))*16+(k0&7)*2;
  unsigned short h0=bf_hi(v0),h1=bf_hi(v1);
  *(unsigned*)(h9+off)=(unsigned)h0|((unsigned)h1<<16);
  *(unsigned*)(h9+off+2048)=(unsigned)bf_hi(v0-bf_f(h0))|((unsigned)bf_hi(v1-bf_f(h1))<<16);
}
// write 4 consecutive k (k0 multiple of 4, same 8-k block): packed 8B hi + 8B lo
__device__ __forceinline__ void h9_w4c(char* h9,int slot,int row,int k0,vf4 v){
  int off=slot*4096+(row*8+((k0>>3)^(row&7)))*16+(k0&7)*2;
  unsigned short h0=bf_hi(v[0]),h1=bf_hi(v[1]),h2=bf_hi(v[2]),h3=bf_hi(v[3]);
  uint2 hv; hv.x=(unsigned)h0|((unsigned)h1<<16); hv.y=(unsigned)h2|((unsigned)h3<<16);
  *(uint2*)(h9+off)=hv;
  uint2 lv;
  lv.x=(unsigned)bf_hi(v[0]-bf_f(h0))|((unsigned)bf_hi(v[1]-bf_f(h1))<<16);
  lv.y=(unsigned)bf_hi(v[2]-bf_f(h2))|((unsigned)bf_hi(v[3]-bf_f(h3))<<16);
  *(uint2*)(h9+off+2048)=lv;
}
__device__ __forceinline__ float h9_rd(const char* h9,int slot,int row,int k){
  int off=slot*4096+(row*8+((k>>3)^(row&7)))*16+(k&7)*2;
  return bf_f(*(const unsigned short*)(h9+off))+bf_f(*(const unsigned short*)(h9+off+2048));
}

struct Ptrs {
  const unsigned short* Wm; const unsigned short* Wa; const unsigned short* Xf;
  const float* Fbp; const float* bqk; const float* f1b;
  const float* m1w; const float* m1b; const float* m2w; const float* m2b;
  float* out;
};

__global__ __launch_bounds__(NTHR,4) void fused_kernel(Ptrs P){
  __shared__ __align__(16) char  h9[77824];     // 19 slots x 4KB
  __shared__ __align__(16) float pbuf[128];

  const int tid=threadIdx.x;
  const int r0=blockIdx.x*R_WG;
  const int w=tid>>6, ln=tid&63;
  const bool w4=(w<4);
  const int arow=ln&15, kb=ln>>4;
  const int rowL=ln&15;                                    // batch row owned (swapped C: col=lane&15)
  const int uA=((2*w)>>2)*16 + (ln>>4)*4 + ((2*w)&3);      // LSTM u for a0 (a1 = uA+1)
  const int ub=(w&3)*16 + (ln>>4)*4;                       // attn u base (4 consecutive)
  const char* Wmb=(const char*)P.Wm;
  // attention weight base: [cidx][colblk=w&3][jblk 0..3][lane], imm offsets j*1024
  const char* awb=(const char*)P.Wa + ((size_t)(w&3))*4096 + (size_t)ln*16;
  const char* Xfb=(const char*)P.Xf + (size_t)(r0+arow)*9*24*32;
  float* qkf=(float*)(h9+10*4096);                         // region R as fp32 qk

  const vf4 bqk4=*(const vf4*)(P.bqk+ub);
  const vf4 bF4 =*(const vf4*)(P.Fbp+ub);
  const vf4 bf14=*(const vf4*)(P.f1b+ub);

  float cst[9][2];
  #pragma unroll
  for(int l=0;l<9;l++){ cst[l][0]=0.f; cst[l][1]=0.f; }

  for(int i=tid;i<77824/16;i+=NTHR) ((vi4*)h9)[i]=(vi4){0,0,0,0};
  __syncthreads();   // zeros visible

  // swapped attn GEMM: A = weight frag (imm-offset loads), B = h frag; C[u][batch row]
  auto attn_gemm=[&](int cidx,int slot,vf4 acc)->vf4{
    const char* Wc=awb + (size_t)cidx*16384;
    vi4 Bh,Bl;
    vi4 W0=g16(Wc),W1=g16(Wc+1024),W2=g16(Wc+2048),W3=g16(Wc+3072);
    a_read(h9,slot,0,arow,kb,Bh,Bl);
    acc=mfma16(W0,Bh,acc); acc=mfma16(W0,Bl,acc); acc=mfma16(W1,Bh,acc);
    a_read(h9,slot,1,arow,kb,Bh,Bl);
    acc=mfma16(W2,Bh,acc); acc=mfma16(W2,Bl,acc); acc=mfma16(W3,Bh,acc);
    return acc;
  };

  for(int t=0;t<T_SZ;t++){
    // ===== 9 LSTMs (swapped operands): read X(1..8)/slot0, write Y(11..18)/slot9 =====
    #pragma unroll
    for(int l=0;l<9;l++){
      const int slotA=(l==0)?0:l;       // fused input
      const int slotW=(l==0)?9:(10+l);  // raw output
      // lane-contiguous layout: [lt][wave][jj 0..11][lane]; per-ks window, imm offsets
      const char* Wl=Wmb + (((size_t)(l*12+t)*8 + w)*12288) + (size_t)ln*16;
      vf4 a0={0,0,0,0},a1={0,0,0,0};
      vi4 Bh,Bl,Wh0,Wh1,Wl0,Wl1;
      // ks0: jj 0..3
      Wh0=g16(Wl); Wh1=g16(Wl+1024); Wl0=g16(Wl+2048); Wl1=g16(Wl+3072);
      a_read(h9,slotA,0,arow,kb,Bh,Bl);
      a0=mfma16(Wh0,Bh,a0); a0=mfma16(Wh0,Bl,a0); a0=mfma16(Wl0,Bh,a0);
      a1=mfma16(Wh1,Bh,a1); a1=mfma16(Wh1,Bl,a1); a1=mfma16(Wl1,Bh,a1);
      // ks1: jj 4..7
      {
        const char* Wk=Wl+4096;
        Wh0=g16(Wk); Wh1=g16(Wk+1024); Wl0=g16(Wk+2048); Wl1=g16(Wk+3072);
      }
      a_read(h9,slotA,1,arow,kb,Bh,Bl);
      a0=mfma16(Wh0,Bh,a0); a0=mfma16(Wh0,Bl,a0); a0=mfma16(Wl0,Bh,a0);
      a1=mfma16(Wh1,Bh,a1); a1=mfma16(Wh1,Bl,a1); a1=mfma16(Wl1,Bh,a1);
      // ks2: jj 8..11 ; B = [x(16) | bias-1 | 0] pre-split frags
      {
        const char* Wk=Wl+8192;
        Wh0=g16(Wk); Wh1=g16(Wk+1024); Wl0=g16(Wk+2048); Wl1=g16(Wk+3072);
      }
      if(kb<2){
        const char* xp=Xfb + (size_t)(l*24 + t*2 + kb)*32;
        Bh=g16(xp); Bl=g16(xp+16);
      } else if(kb==2){ Bh=(vi4){0x3F80,0,0,0}; Bl=(vi4){0,0,0,0}; }
      else            { Bh=(vi4){0,0,0,0};     Bl=(vi4){0,0,0,0}; }
      a0=mfma16(Wh0,Bh,a0); a0=mfma16(Wh0,Bl,a0); a0=mfma16(Wl0,Bh,a0);
      a1=mfma16(Wh1,Bh,a1); a1=mfma16(Wh1,Bl,a1); a1=mfma16(Wl1,Bh,a1);
      // nonlin: gates land directly in acc[0..3] (i,f,g,o)
      {
        float iv=sigm(a0[0]), fv=sigm(a0[1]), gv=tanh_f(a0[2]), ov=sigm(a0[3]);
        float c20=fv*cst[l][0]+iv*gv;
        cst[l][0]=c20;
        float h0v=ov*tanh_f(c20);
        iv=sigm(a1[0]); fv=sigm(a1[1]); gv=tanh_f(a1[2]); ov=sigm(a1[3]);
        float c21=fv*cst[l][1]+iv*gv;
        cst[l][1]=c21;
        float h1v=ov*tanh_f(c21);
        h9_w2(h9,slotW,rowL,uA,h0v,h1v);
      }
      __syncthreads();   // per-l skew bound (replay-stable R14/R15 discipline)
    }

    const bool dofuse=(t<T_SZ-1);
    vf4 g1,g2,g3,g4,g5,g6,g7,g8;   // fusion results held in regs across phS/phH
    // ===== window 1: phKQ (w0-3) CONCURRENT with f_ts+fusion-compute (w4-7) =====
    if(w4){
      vf4 aq=attn_gemm(0, 9, bqk4);   // qk = h_ts@QKc + bqk, C[u][row]
      *(vf4*)(qkf + rowL*64 + ub) = aq;
    } else if(dofuse){
      vf4 facc=attn_gemm(3, 9, bf14); // f_ts
      const char* Wc=awb + (size_t)4*16384;
      vi4 W0=g16(Wc),W1=g16(Wc+1024),W2=g16(Wc+2048),W3=g16(Wc+3072);
      vi4 Bh,Bl;
      g1=facc;g2=facc;g3=facc;g4=facc;g5=facc;g6=facc;g7=facc;g8=facc;
      #define FUSE(gn,slot) \
        a_read(h9,slot,0,arow,kb,Bh,Bl); \
        gn=mfma16(W0,Bh,gn); gn=mfma16(W0,Bl,gn); gn=mfma16(W1,Bh,gn); \
        a_read(h9,slot,1,arow,kb,Bh,Bl); \
        gn=mfma16(W2,Bh,gn); gn=mfma16(W2,Bl,gn); gn=mfma16(W3,Bh,gn);
      FUSE(g1,11) FUSE(g2,12) FUSE(g3,13) FUSE(g4,14)
      FUSE(g5,15) FUSE(g6,16) FUSE(g7,17) FUSE(g8,18)
      #undef FUSE
    }
    __syncthreads();   // b3: qk visible; fusion g's safely in regs
    // ===== phS: scores + softmax -> pbuf, ALL 512 threads (4 threads per (row,n)) =====
    {
      const int sub=tid&3, pair=tid>>2;
      const int rr=pair>>3, nn=pair&7;
      const char* hp=h9+(11+nn)*4096;
      float s=0.f;
      #pragma unroll
      for(int ii=0;ii<2;ii++){
        int kbl=sub*2+ii;
        int blk=kbl^(rr&7);
        const char* pp=hp+(rr*8+blk)*16;
        vi4 hv=*(const vi4*)pp;
        vi4 lv=*(const vi4*)(pp+2048);
        const vf4* qkp=(const vf4*)(qkf+rr*64+kbl*8);
        vf4 q0=qkp[0], q1=qkp[1];
        #pragma unroll
        for(int e=0;e<4;e++){
          unsigned hw=((const unsigned*)&hv)[e], lw=((const unsigned*)&lv)[e];
          float w0=__uint_as_float(hw<<16)+__uint_as_float(lw<<16);
          float w1=__uint_as_float(hw&0xffff0000u)+__uint_as_float(lw&0xffff0000u);
          float qa=(e<2)? q0[e*2] : q1[(e-2)*2];
          float qb=(e<2)? q0[e*2+1] : q1[(e-2)*2+1];
          s+=w0*qa+w1*qb;
        }
      }
      s+=__shfl_xor(s,1); s+=__shfl_xor(s,2);        // k-reduce (4 subs)
      float mx=s;
      mx=fmaxf(mx,__shfl_xor(mx,4));
      mx=fmaxf(mx,__shfl_xor(mx,8));
      mx=fmaxf(mx,__shfl_xor(mx,16));
      float e=__expf(s-mx);
      float sm=e;
      sm+=__shfl_xor(sm,4); sm+=__shfl_xor(sm,8); sm+=__shfl_xor(sm,16);
      if(sub==0) pbuf[pair]=e/sm;
    }
    __syncthreads();   // b4: p visible; all qkf reads done
    // ===== phH: hbar -> region R (split-bf16), ALL 8 waves, 2 rows each =====
    {
      #pragma unroll
      for(int ri=0;ri<2;ri++){
        int row=w*2+ri;
        float sa=0.f;
        #pragma unroll
        for(int n=0;n<8;n++) sa+=pbuf[row*8+n]*h9_rd(h9,11+n,row,ln);
        h9_w1(h9,10,row,ln,sa);
      }
    }
    __syncthreads();   // b5: hbar visible
    // ===== phC+phB (w0-3) -> slot0 ; CONCURRENT X-writes from g-regs (w4-7) =====
    if(w4){
      vf4 acA=attn_gemm(1, 10, bF4);
      acA=attn_gemm(2, 9, acA);
      acA[0]=fmaxf(acA[0],0.f); acA[1]=fmaxf(acA[1],0.f);
      acA[2]=fmaxf(acA[2],0.f); acA[3]=fmaxf(acA[3],0.f);
      h9_w4c(h9,0,rowL,ub,acA);
    } else if(dofuse){
      #define WRX(gn,slot) \
        gn[0]=fmaxf(gn[0],0.f); gn[1]=fmaxf(gn[1],0.f); \
        gn[2]=fmaxf(gn[2],0.f); gn[3]=fmaxf(gn[3],0.f); \
        h9_w4c(h9,slot,rowL,ub,gn);
      WRX(g1,1) WRX(g2,2) WRX(g3,3) WRX(g4,4)
      WRX(g5,5) WRX(g6,6) WRX(g7,7) WRX(g8,8)
      #undef WRX
    }
    __syncthreads();   // b6: slot0 + X visible for next t / MLP
  }

  // ===== final MLP from slot0 (h_tsa) =====
  {
    float* hid=(float*)(h9+10*4096);   // region R dead
    int rr=tid>>5, ii=tid&31;
    float h=P.m1b[ii];
    for(int k=0;k<64;k++) h+=h9_rd(h9,0,rr,k)*P.m1w[(size_t)ii*64+k];
    hid[rr*32+ii]=fmaxf(h,0.f);
    __syncthreads();
    if(tid<R_WG){
      float s=P.m2b[0];
      for(int i=0;i<32;i++) s+=hid[tid*32+i]*P.m2w[i];
      P.out[r0+tid]=s;
    }
  }
}

// ---- prep: LSTM weight frags, lane-contiguous layout [lt][wave][jj][lane][8] ----
// jj = 4*ks + 2*split + (block&1); wave = block>>1; bias folded at k=80
__global__ void prep_wm(const float* eW, const float* eU, const float* e2W, const float* e2U,
                        const float* emb_w, const float* eb_ih, const float* eb_hh,
                        const float* e2b_ih, const float* e2b_hh, const float* emb_b,
                        unsigned short* dst){
  int id=blockIdx.x*256+threadIdx.x;
  if(id>=108*3*16*64) return;
  int lane=id&63;
  int q=id>>6;
  int wnt=q&15;
  int q2=q>>4;
  int ks=q2%3;
  int lt=q2/3;
  int LL=lt/12, t=lt%12;
  int c15=lane&15;
  int u=(wnt>>2)*16+(c15>>2)*4+(wnt&3);
  int gt=c15&3;
  int jg=gt*64+u;
  const float* Whh=(LL==0)? eU+((size_t)t*256+jg)*64 : e2U+(((size_t)(LL-1)*12+t)*256+jg)*64;
  const float* Wih=(LL==0)? eW+((size_t)t*256+jg)*32 : e2W+(((size_t)(LL-1)*12+t)*256+jg)*32;
  float bsum;
  {
    float bi=(LL==0)? eb_ih[t*256+jg] : e2b_ih[((LL-1)*12+t)*256+jg];
    float bh=(LL==0)? eb_hh[t*256+jg] : e2b_hh[((LL-1)*12+t)*256+jg];
    float s=bi+bh;
    for(int i=0;i<32;i++) s+=Wih[i]*emb_b[i];
    bsum=s;
  }
  int wv=wnt>>1, p=wnt&1;
  size_t base_hi=(((size_t)lt*8+wv)*12 + (4*ks+p  ))*512 + (size_t)lane*8;
  size_t base_lo=(((size_t)lt*8+wv)*12 + (4*ks+2+p))*512 + (size_t)lane*8;
  #pragma unroll
  for(int j=0;j<8;j++){
    int k=ks*32+(lane>>4)*8+j;
    float v;
    if(k<64) v=Whh[k];
    else if(k<80){
      int kx=k-64; float s=0.f;
      for(int i=0;i<32;i++) s+=Wih[i]*emb_w[i*16+kx];
      v=s;
    } else if(k==80) v=bsum;
    else v=0.f;
    unsigned short hi=bf_hi(v), lo=bf_hi(v-bf_f(hi));
    dst[base_hi+j]=hi;
    dst[base_lo+j]=lo;
  }
}

// ---- prep: 5 attention/fusion chunks, layout [cidx][colblk][q][lane][8], + Fbp + bqk ----
// cidx: 0=QKc(0.125*Qw.T@Kw), 1=VFc(FwA@Vw), 2=FBc, 3=F1Bc, 4=F1Ac ; q: 2*ks+split? no: q=(ks<<1)|split order ks0hi,ks0lo,ks1hi,ks1lo
__global__ void prep_attw(const float* Qw, const float* Qb, const float* Kw,
                          const float* Vw, const float* Vb,
                          const float* Fw, const float* Fb, const float* f1w,
                          unsigned short* dst, float* Fbp, float* bqk){
  int id=blockIdx.x*256+threadIdx.x;
  if(id<5120){
    int cidx=id>>10;
    int rem=id&1023;
    int block=rem>>6;
    int lane=rem&63;
    int ks=(block>>1)&1, s=block&1;
    int cb=block>>2;
    int qq=(ks<<1)|s;          // 0=ks0hi,1=ks0lo,2=ks1hi,3=ks1lo
    int col=cb*16+(lane&15);
    size_t base=(((size_t)cidx*4+cb)*4 + qq)*512 + (size_t)lane*8;
    #pragma unroll
    for(int j=0;j<8;j++){
      int k=ks*32+(lane>>4)*8+j;
      float v;
      if(cidx==0){ float sv=0.f; for(int m=0;m<64;m++) sv+=Qw[m*64+k]*Kw[m*64+col]; v=sv*0.125f; }
      else if(cidx==1){ float sv=0.f; for(int m=0;m<64;m++) sv+=Fw[col*128+m]*Vw[m*64+k]; v=sv; }
      else if(cidx==2) v=Fw[col*128+64+k];
      else if(cidx==3) v=f1w[col*128+64+k];
      else             v=f1w[col*128+k];
      unsigned short hi=bf_hi(v);
      dst[base+j] = (s==0)? hi : bf_hi(v-bf_f(hi));
    }
  } else if(id<5184){
    int u=id-5120;
    float s=Fb[u];
    for(int m=0;m<64;m++) s+=Fw[u*128+m]*Vb[m];
    Fbp[u]=s;
  } else if(id<5248){
    int m=id-5184;
    float s=0.f;
    for(int u=0;u<64;u++) s+=Qb[u]*Kw[u*64+m];
    bqk[m]=s*0.125f;
  }
}

// ---- prep: x B-fragments pre-split: [b][src 0..8][t][kb]{hi 16B, lo 16B} ----
__global__ void prep_xf(const float* ts, const float* gts, unsigned short* xf){
  int id=blockIdx.x*256+threadIdx.x;
  if(id>=8192*9*24) return;
  int kb=id&1;
  int t=(id>>1)%12;
  int q=id/24;
  int src=q%9;
  int b=q/9;
  const float* s=(src==0)? ts+(size_t)b*192+(size_t)t*16+kb*8
                         : gts+(size_t)b*1536+(size_t)(src-1)*192+(size_t)t*16+kb*8;
  unsigned short* d=xf+(size_t)id*16;
  #pragma unroll
  for(int j=0;j<8;j++){
    float f=s[j];
    unsigned short hi=bf_hi(f);
    d[j]=hi;
    d[8+j]=bf_hi(f-bf_f(hi));
  }
}

extern "C" void kernel_launch(void* const* d_in, const int* in_sizes, int n_in,
                              void* d_out, int out_size, void* d_ws, size_t ws_size,
                              hipStream_t stream){
  const float* ts      =(const float*)d_in[0];
  const float* gts     =(const float*)d_in[1];
  const float* emb_w   =(const float*)d_in[2];
  const float* emb_b   =(const float*)d_in[3];
  const float* attQ_w  =(const float*)d_in[4];
  const float* attQ_b  =(const float*)d_in[5];
  const float* attK_w  =(const float*)d_in[6];
  // d_in[7] attK_b: softmax-invariant, unused
  const float* attV_w  =(const float*)d_in[8];
  const float* attV_b  =(const float*)d_in[9];
  const float* attF_w  =(const float*)d_in[10];
  const float* attF_b  =(const float*)d_in[11];
  const float* fuse1_w =(const float*)d_in[12];
  const float* fuse1_b =(const float*)d_in[13];
  const float* enc_Wih =(const float*)d_in[14];
  const float* enc_Whh =(const float*)d_in[15];
  const float* enc_bih =(const float*)d_in[16];
  const float* enc_bhh =(const float*)d_in[17];
  const float* enc2_Wih=(const float*)d_in[18];
  const float* enc2_Whh=(const float*)d_in[19];
  const float* enc2_bih=(const float*)d_in[20];
  const float* enc2_bhh=(const float*)d_in[21];
  const float* mlp1_w  =(const float*)d_in[22];
  const float* mlp1_b  =(const float*)d_in[23];
  const float* mlp2_w  =(const float*)d_in[24];
  const float* mlp2_b  =(const float*)d_in[25];

  char* ws=(char*)d_ws;
  size_t off=0;
  unsigned short* Wm=(unsigned short*)(ws+off); off+=(size_t)108*6*8192*2;
  unsigned short* Wa=(unsigned short*)(ws+off); off+=(size_t)5*8192*2;
  float* Fbp=(float*)(ws+off); off+=64*4;
  float* bqk=(float*)(ws+off); off+=64*4;
  unsigned short* Xf=(unsigned short*)(ws+off); off+=(size_t)8192*9*24*16*2;

  prep_wm<<<(108*3*16*64+255)/256,256,0,stream>>>(enc_Wih,enc_Whh,enc2_Wih,enc2_Whh,emb_w,
                                                  enc_bih,enc_bhh,enc2_bih,enc2_bhh,emb_b,Wm);
  prep_attw<<<21,256,0,stream>>>(attQ_w,attQ_b,attK_w,attV_w,attV_b,attF_w,attF_b,fuse1_w,
                                 Wa,Fbp,bqk);
  prep_xf<<<(8192*9*24+255)/256,256,0,stream>>>(ts,gts,Xf);

  Ptrs P;
  P.Wm=Wm; P.Wa=Wa; P.Xf=Xf;
  P.Fbp=Fbp; P.bqk=bqk; P.f1b=fuse1_b;
  P.m1w=mlp1_w; P.m1b=mlp1_b; P.m2w=mlp2_w; P.m2b=mlp2_b;
  P.out=(float*)d_out;

  fused_kernel<<<NWG,NTHR,0,stream>>>(P);
}

// Round 17
// 432.205 us; speedup vs baseline: 1.5450x; 1.0236x over previous
//
#include <hip/hip_runtime.h>

#define T_SZ 12
#define R_WG 16
#define NTHR 512
#define NWG  512   // 8192/16

typedef float  vf4 __attribute__((ext_vector_type(4)));
typedef int    vi4 __attribute__((ext_vector_type(4)));
typedef __bf16 vbf8 __attribute__((ext_vector_type(8)));

__device__ __forceinline__ float sigm(float x){ return 1.f/(1.f+__expf(-x)); }
__device__ __forceinline__ float tanh_f(float x){
  float e=__expf(2.f*x); return 1.f - 2.f/(e+1.f);
}
// HW RNE f32->bf16 (v_cvt_bf16_f32 / pk form), 1 op vs manual 3-4 op RNE
__device__ __forceinline__ unsigned short bf_hi(float f){
  return __builtin_bit_cast(unsigned short,(__bf16)f);
}
__device__ __forceinline__ float bf_f(unsigned short h){
  return __uint_as_float(((unsigned int)h)<<16);
}
__device__ __forceinline__ vf4 mfma16(vi4 a, vi4 b, vf4 c){
  return __builtin_amdgcn_mfma_f32_16x16x32_bf16(
      __builtin_bit_cast(vbf8,a), __builtin_bit_cast(vbf8,b), c, 0, 0, 0);
}
__device__ __forceinline__ vi4 g16(const char* p){ return *(const vi4*)p; }

// split-bf16 h slots: slot*4096 + [split +2048] + (row*8 + ((k>>3)^(row&7)))*16 + (k&7)*2
// slots: 0=h_tsa, 1..8=X fused nodes, 9=h_ts, 10=R (qk fp32 / hbar), 11..18=Y raw nodes
__device__ __forceinline__ void a_read(const char* h9,int slot,int ks,int arow,int kb,vi4& Ah,vi4& Al){
  int blk=((ks<<2)+kb)^(arow&7);
  const char* p=h9+slot*4096+(arow*8+blk)*16;
  Ah=*(const vi4*)p; Al=*(const vi4*)(p+2048);
}
__device__ __forceinline__ void h9_w1(char* h9,int slot,int row,int k,float v){
  int off=slot*4096+(row*8+((k>>3)^(row&7)))*16+(k&7)*2;
  unsigned short hi=bf_hi(v);
  *(unsigned short*)(h9+off)=hi;
  *(unsigned short*)(h9+off+2048)=bf_hi(v-bf_f(hi));
}
__device__ __forceinline__ void h9_w2(char* h9,int slot,int row,int k0,float v0,float v1){
  int off=slot*4096+(row*8+((k0>>3)^(row&7)))*16+(k0&7)*2;
  unsigned short h0=bf_hi(v0),h1=bf_hi(v1);
  *(unsigned*)(h9+off)=(unsigned)h0|((unsigned)h1<<16);
  *(unsigned*)(h9+off+2048)=(unsigned)bf_hi(v0-bf_f(h0))|((unsigned)bf_hi(v1-bf_f(h1))<<16);
}
// write 4 consecutive k (k0 multiple of 4, same 8-k block): packed 8B hi + 8B lo
__device__ __forceinline__ void h9_w4c(char* h9,int slot,int row,int k0,vf4 v){
  int off=slot*4096+(row*8+((k0>>3)^(row&7)))*16+(k0&7)*2;
  unsigned short h0=bf_hi(v[0]),h1=bf_hi(v[1]),h2=bf_hi(v[2]),h3=bf_hi(v[3]);
  uint2 hv; hv.x=(unsigned)h0|((unsigned)h1<<16); hv.y=(unsigned)h2|((unsigned)h3<<16);
  *(uint2*)(h9+off)=hv;
  uint2 lv;
  lv.x=(unsigned)bf_hi(v[0]-bf_f(h0))|((unsigned)bf_hi(v[1]-bf_f(h1))<<16);
  lv.y=(unsigned)bf_hi(v[2]-bf_f(h2))|((unsigned)bf_hi(v[3]-bf_f(h3))<<16);
  *(uint2*)(h9+off+2048)=lv;
}
__device__ __forceinline__ float h9_rd(const char* h9,int slot,int row,int k){
  int off=slot*4096+(row*8+((k>>3)^(row&7)))*16+(k&7)*2;
  return bf_f(*(const unsigned short*)(h9+off))+bf_f(*(const unsigned short*)(h9+off+2048));
}

struct Ptrs {
  const unsigned short* Wm; const unsigned short* Wa; const unsigned short* Xf;
  const float* Fbp; const float* bqk; const float* f1b;
  const float* m1w; const float* m1b; const float* m2w; const float* m2b;
  float* out;
};

__global__ __launch_bounds__(NTHR,4) void fused_kernel(Ptrs P){
  __shared__ __align__(16) char  h9[77824];     // 19 slots x 4KB
  __shared__ __align__(16) float pbuf[128];

  const int tid=threadIdx.x;
  const int r0=blockIdx.x*R_WG;
  const int w=tid>>6, ln=tid&63;
  const bool w4=(w<4);
  const int arow=ln&15, kb=ln>>4;
  const int rowL=ln&15;                                    // batch row owned (swapped C)
  const int uA=((2*w)>>2)*16 + (ln>>4)*4 + ((2*w)&3);      // LSTM u for a0 (a1 = uA+1)
  const int ub=(w&3)*16 + (ln>>4)*4;                       // attn u base (4 consecutive)
  const char* Wmb=(const char*)P.Wm;
  const char* awb=(const char*)P.Wa + ((size_t)(w&3))*4096 + (size_t)ln*16;
  const char* Xfb=(const char*)P.Xf + (size_t)(r0+arow)*9*24*32;
  float* qkf=(float*)(h9+10*4096);                         // region R as fp32 qk

  const vf4 bqk4=*(const vf4*)(P.bqk+ub);
  const vf4 bF4 =*(const vf4*)(P.Fbp+ub);
  const vf4 bf14=*(const vf4*)(P.f1b+ub);

  float cst[9][2];
  #pragma unroll
  for(int l=0;l<9;l++){ cst[l][0]=0.f; cst[l][1]=0.f; }

  for(int i=tid;i<77824/16;i+=NTHR) ((vi4*)h9)[i]=(vi4){0,0,0,0};
  __syncthreads();   // zeros visible

  auto attn_gemm=[&](int cidx,int slot,vf4 acc)->vf4{
    const char* Wc=awb + (size_t)cidx*16384;
    vi4 Bh,Bl;
    vi4 W0=g16(Wc),W1=g16(Wc+1024),W2=g16(Wc+2048),W3=g16(Wc+3072);
    a_read(h9,slot,0,arow,kb,Bh,Bl);
    acc=mfma16(W0,Bh,acc); acc=mfma16(W0,Bl,acc); acc=mfma16(W1,Bh,acc);
    a_read(h9,slot,1,arow,kb,Bh,Bl);
    acc=mfma16(W2,Bh,acc); acc=mfma16(W2,Bl,acc); acc=mfma16(W3,Bh,acc);
    return acc;
  };

  for(int t=0;t<T_SZ;t++){
    // ===== 9 LSTMs, ZERO inner barriers: reads {slot0,1..8} / writes {9,11..18} disjoint =====
    // (isolated retry of R13 delta (a); X-writes stay deferred, phH stays all-wave)
    #pragma unroll
    for(int l=0;l<9;l++){
      const int slotA=(l==0)?0:l;       // fused input
      const int slotW=(l==0)?9:(10+l);  // raw output
      const char* Wl=Wmb + (((size_t)(l*12+t)*8 + w)*12288) + (size_t)ln*16;
      vf4 a0={0,0,0,0},a1={0,0,0,0};
      vi4 Bh,Bl,Wh0,Wh1,Wl0,Wl1;
      // ks0: jj 0..3
      Wh0=g16(Wl); Wh1=g16(Wl+1024); Wl0=g16(Wl+2048); Wl1=g16(Wl+3072);
      a_read(h9,slotA,0,arow,kb,Bh,Bl);
      a0=mfma16(Wh0,Bh,a0); a0=mfma16(Wh0,Bl,a0); a0=mfma16(Wl0,Bh,a0);
      a1=mfma16(Wh1,Bh,a1); a1=mfma16(Wh1,Bl,a1); a1=mfma16(Wl1,Bh,a1);
      // ks1: jj 4..7
      {
        const char* Wk=Wl+4096;
        Wh0=g16(Wk); Wh1=g16(Wk+1024); Wl0=g16(Wk+2048); Wl1=g16(Wk+3072);
      }
      a_read(h9,slotA,1,arow,kb,Bh,Bl);
      a0=mfma16(Wh0,Bh,a0); a0=mfma16(Wh0,Bl,a0); a0=mfma16(Wl0,Bh,a0);
      a1=mfma16(Wh1,Bh,a1); a1=mfma16(Wh1,Bl,a1); a1=mfma16(Wl1,Bh,a1);
      // ks2: jj 8..11 ; B = [x(16) | bias-1 | 0] pre-split frags
      {
        const char* Wk=Wl+8192;
        Wh0=g16(Wk); Wh1=g16(Wk+1024); Wl0=g16(Wk+2048); Wl1=g16(Wk+3072);
      }
      if(kb<2){
        const char* xp=Xfb + (size_t)(l*24 + t*2 + kb)*32;
        Bh=g16(xp); Bl=g16(xp+16);
      } else if(kb==2){ Bh=(vi4){0x3F80,0,0,0}; Bl=(vi4){0,0,0,0}; }
      else            { Bh=(vi4){0,0,0,0};     Bl=(vi4){0,0,0,0}; }
      a0=mfma16(Wh0,Bh,a0); a0=mfma16(Wh0,Bl,a0); a0=mfma16(Wl0,Bh,a0);
      a1=mfma16(Wh1,Bh,a1); a1=mfma16(Wh1,Bl,a1); a1=mfma16(Wl1,Bh,a1);
      // nonlin: gates land directly in acc[0..3] (i,f,g,o)
      {
        float iv=sigm(a0[0]), fv=sigm(a0[1]), gv=tanh_f(a0[2]), ov=sigm(a0[3]);
        float c20=fv*cst[l][0]+iv*gv;
        cst[l][0]=c20;
        float h0v=ov*tanh_f(c20);
        iv=sigm(a1[0]); fv=sigm(a1[1]); gv=tanh_f(a1[2]); ov=sigm(a1[3]);
        float c21=fv*cst[l][1]+iv*gv;
        cst[l][1]=c21;
        float h1v=ov*tanh_f(c21);
        h9_w2(h9,slotW,rowL,uA,h0v,h1v);
      }
    }
    __syncthreads();   // b2: all raw h (Y, slot9) visible

    const bool dofuse=(t<T_SZ-1);
    vf4 g1,g2,g3,g4,g5,g6,g7,g8;   // fusion results held in regs across phS/phH
    // ===== window 1 (rebalanced): w0-3: phKQ + f_ts + FUSE 1-3 ; w4-7: f_ts + FUSE 4-8 =====
    #define FUSE(gn,slot) \
      a_read(h9,slot,0,arow,kb,Bh,Bl); \
      gn=mfma16(W0,Bh,gn); gn=mfma16(W0,Bl,gn); gn=mfma16(W1,Bh,gn); \
      a_read(h9,slot,1,arow,kb,Bh,Bl); \
      gn=mfma16(W2,Bh,gn); gn=mfma16(W2,Bl,gn); gn=mfma16(W3,Bh,gn);
    if(w4){
      vf4 aq=attn_gemm(0, 9, bqk4);   // qk = h_ts@QKc + bqk, C[u][row]
      *(vf4*)(qkf + rowL*64 + ub) = aq;
      if(dofuse){
        vf4 facc=attn_gemm(3, 9, bf14);
        const char* Wc=awb + (size_t)4*16384;
        vi4 W0=g16(Wc),W1=g16(Wc+1024),W2=g16(Wc+2048),W3=g16(Wc+3072);
        vi4 Bh,Bl;
        g1=facc;g2=facc;g3=facc;
        FUSE(g1,11) FUSE(g2,12) FUSE(g3,13)
      }
    } else if(dofuse){
      vf4 facc=attn_gemm(3, 9, bf14);
      const char* Wc=awb + (size_t)4*16384;
      vi4 W0=g16(Wc),W1=g16(Wc+1024),W2=g16(Wc+2048),W3=g16(Wc+3072);
      vi4 Bh,Bl;
      g4=facc;g5=facc;g6=facc;g7=facc;g8=facc;
      FUSE(g4,14) FUSE(g5,15) FUSE(g6,16) FUSE(g7,17) FUSE(g8,18)
    }
    #undef FUSE
    __syncthreads();   // b3: qk visible; fusion g's safely in regs
    // ===== phS: scores + softmax -> pbuf, ALL 512 threads (4 threads per (row,n)) =====
    {
      const int sub=tid&3, pair=tid>>2;
      const int rr=pair>>3, nn=pair&7;
      const char* hp=h9+(11+nn)*4096;
      float s=0.f;
      #pragma unroll
      for(int ii=0;ii<2;ii++){
        int kbl=sub*2+ii;
        int blk=kbl^(rr&7);
        const char* pp=hp+(rr*8+blk)*16;
        vi4 hv=*(const vi4*)pp;
        vi4 lv=*(const vi4*)(pp+2048);
        const vf4* qkp=(const vf4*)(qkf+rr*64+kbl*8);
        vf4 q0=qkp[0], q1=qkp[1];
        #pragma unroll
        for(int e=0;e<4;e++){
          unsigned hw=((const unsigned*)&hv)[e], lw=((const unsigned*)&lv)[e];
          float w0=__uint_as_float(hw<<16)+__uint_as_float(lw<<16);
          float w1=__uint_as_float(hw&0xffff0000u)+__uint_as_float(lw&0xffff0000u);
          float qa=(e<2)? q0[e*2] : q1[(e-2)*2];
          float qb=(e<2)? q0[e*2+1] : q1[(e-2)*2+1];
          s+=w0*qa+w1*qb;
        }
      }
      s+=__shfl_xor(s,1); s+=__shfl_xor(s,2);        // k-reduce (4 subs)
      float mx=s;
      mx=fmaxf(mx,__shfl_xor(mx,4));
      mx=fmaxf(mx,__shfl_xor(mx,8));
      mx=fmaxf(mx,__shfl_xor(mx,16));
      float e=__expf(s-mx);
      float sm=e;
      sm+=__shfl_xor(sm,4); sm+=__shfl_xor(sm,8); sm+=__shfl_xor(sm,16);
      if(sub==0) pbuf[pair]=e/sm;
    }
    __syncthreads();   // b4: p visible; all qkf reads done
    // ===== phH: hbar -> region R (split-bf16), ALL 8 waves, 2 rows each =====
    {
      #pragma unroll
      for(int ri=0;ri<2;ri++){
        int row=w*2+ri;
        float sa=0.f;
        #pragma unroll
        for(int n=0;n<8;n++) sa+=pbuf[row*8+n]*h9_rd(h9,11+n,row,ln);
        h9_w1(h9,10,row,ln,sa);
      }
    }
    __syncthreads();   // b5: hbar visible
    // ===== phC+phB (w0-3) -> slot0 + X1-3 ; w4-7: X4-8 writes =====
    #define WRX(gn,slot) \
      gn[0]=fmaxf(gn[0],0.f); gn[1]=fmaxf(gn[1],0.f); \
      gn[2]=fmaxf(gn[2],0.f); gn[3]=fmaxf(gn[3],0.f); \
      h9_w4c(h9,slot,rowL,ub,gn);
    if(w4){
      vf4 acA=attn_gemm(1, 10, bF4);
      acA=attn_gemm(2, 9, acA);
      acA[0]=fmaxf(acA[0],0.f); acA[1]=fmaxf(acA[1],0.f);
      acA[2]=fmaxf(acA[2],0.f); acA[3]=fmaxf(acA[3],0.f);
      h9_w4c(h9,0,rowL,ub,acA);
      if(dofuse){ WRX(g1,1) WRX(g2,2) WRX(g3,3) }
    } else if(dofuse){
      WRX(g4,4) WRX(g5,5) WRX(g6,6) WRX(g7,7) WRX(g8,8)
    }
    #undef WRX
    __syncthreads();   // b6: slot0 + X visible for next t / MLP
  }

  // ===== final MLP from slot0 (h_tsa) =====
  {
    float* hid=(float*)(h9+10*4096);   // region R dead
    int rr=tid>>5, ii=tid&31;
    float h=P.m1b[ii];
    for(int k=0;k<64;k++) h+=h9_rd(h9,0,rr,k)*P.m1w[(size_t)ii*64+k];
    hid[rr*32+ii]=fmaxf(h,0.f);
    __syncthreads();
    if(tid<R_WG){
      float s=P.m2b[0];
      for(int i=0;i<32;i++) s+=hid[tid*32+i]*P.m2w[i];
      P.out[r0+tid]=s;
    }
  }
}

// ---- prep: LSTM weight frags, lane-contiguous layout [lt][wave][jj][lane][8] ----
__global__ void prep_wm(const float* eW, const float* eU, const float* e2W, const float* e2U,
                        const float* emb_w, const float* eb_ih, const float* eb_hh,
                        const float* e2b_ih, const float* e2b_hh, const float* emb_b,
                        unsigned short* dst){
  int id=blockIdx.x*256+threadIdx.x;
  if(id>=108*3*16*64) return;
  int lane=id&63;
  int q=id>>6;
  int wnt=q&15;
  int q2=q>>4;
  int ks=q2%3;
  int lt=q2/3;
  int LL=lt/12, t=lt%12;
  int c15=lane&15;
  int u=(wnt>>2)*16+(c15>>2)*4+(wnt&3);
  int gt=c15&3;
  int jg=gt*64+u;
  const float* Whh=(LL==0)? eU+((size_t)t*256+jg)*64 : e2U+(((size_t)(LL-1)*12+t)*256+jg)*64;
  const float* Wih=(LL==0)? eW+((size_t)t*256+jg)*32 : e2W+(((size_t)(LL-1)*12+t)*256+jg)*32;
  float bsum;
  {
    float bi=(LL==0)? eb_ih[t*256+jg] : e2b_ih[((LL-1)*12+t)*256+jg];
    float bh=(LL==0)? eb_hh[t*256+jg] : e2b_hh[((LL-1)*12+t)*256+jg];
    float s=bi+bh;
    for(int i=0;i<32;i++) s+=Wih[i]*emb_b[i];
    bsum=s;
  }
  int wv=wnt>>1, p=wnt&1;
  size_t base_hi=(((size_t)lt*8+wv)*12 + (4*ks+p  ))*512 + (size_t)lane*8;
  size_t base_lo=(((size_t)lt*8+wv)*12 + (4*ks+2+p))*512 + (size_t)lane*8;
  #pragma unroll
  for(int j=0;j<8;j++){
    int k=ks*32+(lane>>4)*8+j;
    float v;
    if(k<64) v=Whh[k];
    else if(k<80){
      int kx=k-64; float s=0.f;
      for(int i=0;i<32;i++) s+=Wih[i]*emb_w[i*16+kx];
      v=s;
    } else if(k==80) v=bsum;
    else v=0.f;
    unsigned short hi=bf_hi(v), lo=bf_hi(v-bf_f(hi));
    dst[base_hi+j]=hi;
    dst[base_lo+j]=lo;
  }
}

// ---- prep: 5 attention/fusion chunks, layout [cidx][colblk][q][lane][8], + Fbp + bqk ----
// cidx: 0=QKc(0.125*Qw.T@Kw), 1=VFc(FwA@Vw), 2=FBc, 3=F1Bc, 4=F1Ac
__global__ void prep_attw(const float* Qw, const float* Qb, const float* Kw,
                          const float* Vw, const float* Vb,
                          const float* Fw, const float* Fb, const float* f1w,
                          unsigned short* dst, float* Fbp, float* bqk){
  int id=blockIdx.x*256+threadIdx.x;
  if(id<5120){
    int cidx=id>>10;
    int rem=id&1023;
    int block=rem>>6;
    int lane=rem&63;
    int ks=(block>>1)&1, s=block&1;
    int cb=block>>2;
    int qq=(ks<<1)|s;
    int col=cb*16+(lane&15);
    size_t base=(((size_t)cidx*4+cb)*4 + qq)*512 + (size_t)lane*8;
    #pragma unroll
    for(int j=0;j<8;j++){
      int k=ks*32+(lane>>4)*8+j;
      float v;
      if(cidx==0){ float sv=0.f; for(int m=0;m<64;m++) sv+=Qw[m*64+k]*Kw[m*64+col]; v=sv*0.125f; }
      else if(cidx==1){ float sv=0.f; for(int m=0;m<64;m++) sv+=Fw[col*128+m]*Vw[m*64+k]; v=sv; }
      else if(cidx==2) v=Fw[col*128+64+k];
      else if(cidx==3) v=f1w[col*128+64+k];
      else             v=f1w[col*128+k];
      unsigned short hi=bf_hi(v);
      dst[base+j] = (s==0)? hi : bf_hi(v-bf_f(hi));
    }
  } else if(id<5184){
    int u=id-5120;
    float s=Fb[u];
    for(int m=0;m<64;m++) s+=Fw[u*128+m]*Vb[m];
    Fbp[u]=s;
  } else if(id<5248){
    int m=id-5184;
    float s=0.f;
    for(int u=0;u<64;u++) s+=Qb[u]*Kw[u*64+m];
    bqk[m]=s*0.125f;
  }
}

// ---- prep: x B-fragments pre-split: [b][src 0..8][t][kb]{hi 16B, lo 16B} ----
__global__ void prep_xf(const float* ts, const float* gts, unsigned short* xf){
  int id=blockIdx.x*256+threadIdx.x;
  if(id>=8192*9*24) return;
  int kb=id&1;
  int t=(id>>1)%12;
  int q=id/24;
  int src=q%9;
  int b=q/9;
  const float* s=(src==0)? ts+(size_t)b*192+(size_t)t*16+kb*8
                         : gts+(size_t)b*1536+(size_t)(src-1)*192+(size_t)t*16+kb*8;
  unsigned short* d=xf+(size_t)id*16;
  #pragma unroll
  for(int j=0;j<8;j++){
    float f=s[j];
    unsigned short hi=bf_hi(f);
    d[j]=hi;
    d[8+j]=bf_hi(f-bf_f(hi));
  }
}

extern "C" void kernel_launch(void* const* d_in, const int* in_sizes, int n_in,
                              void* d_out, int out_size, void* d_ws, size_t ws_size,
                              hipStream_t stream){
  const float* ts      =(const float*)d_in[0];
  const float* gts     =(const float*)d_in[1];
  const float* emb_w   =(const float*)d_in[2];
  const float* emb_b   =(const float*)d_in[3];
  const float* attQ_w  =(const float*)d_in[4];
  const float* attQ_b  =(const float*)d_in[5];
  const float* attK_w  =(const float*)d_in[6];
  // d_in[7] attK_b: softmax-invariant, unused
  const float* attV_w  =(const float*)d_in[8];
  const float* attV_b  =(const float*)d_in[9];
  const float* attF_w  =(const float*)d_in[10];
  const float* attF_b  =(const float*)d_in[11];
  const float* fuse1_w =(const float*)d_in[12];
  const float* fuse1_b =(const float*)d_in[13];
  const float* enc_Wih =(const float*)d_in[14];
  const float* enc_Whh =(const float*)d_in[15];
  const float* enc_bih =(const float*)d_in[16];
  const float* enc_bhh =(const float*)d_in[17];
  const float* enc2_Wih=(const float*)d_in[18];
  const float* enc2_Whh=(const float*)d_in[19];
  const float* enc2_bih=(const float*)d_in[20];
  const float* enc2_bhh=(const float*)d_in[21];
  const float* mlp1_w  =(const float*)d_in[22];
  const float* mlp1_b  =(const float*)d_in[23];
  const float* mlp2_w  =(const float*)d_in[24];
  const float* mlp2_b  =(const float*)d_in[25];

  char* ws=(char*)d_ws;
  size_t off=0;
  unsigned short* Wm=(unsigned short*)(ws+off); off+=(size_t)108*6*8192*2;
  unsigned short* Wa=(unsigned short*)(ws+off); off+=(size_t)5*8192*2;
  float* Fbp=(float*)(ws+off); off+=64*4;
  float* bqk=(float*)(ws+off); off+=64*4;
  unsigned short* Xf=(unsigned short*)(ws+off); off+=(size_t)8192*9*24*16*2;

  prep_wm<<<(108*3*16*64+255)/256,256,0,stream>>>(enc_Wih,enc_Whh,enc2_Wih,enc2_Whh,emb_w,
                                                  enc_bih,enc_bhh,enc2_bih,enc2_bhh,emb_b,Wm);
  prep_attw<<<21,256,0,stream>>>(attQ_w,attQ_b,attK_w,attV_w,attV_b,attF_w,attF_b,fuse1_w,
                                 Wa,Fbp,bqk);
  prep_xf<<<(8192*9*24+255)/256,256,0,stream>>>(ts,gts,Xf);

  Ptrs P;
  P.Wm=Wm; P.Wa=Wa; P.Xf=Xf;
  P.Fbp=Fbp; P.bqk=bqk; P.f1b=fuse1_b;
  P.m1w=mlp1_w; P.m1b=mlp1_b; P.m2w=mlp2_w; P.m2b=mlp2_b;
  P.out=(float*)d_out;

  fused_kernel<<<NWG,NTHR,0,stream>>>(P);
}